// Round 4
// baseline (534.865 us; speedup 1.0000x reference)
//
#include <hip/hip_runtime.h>
#include <hip/hip_bf16.h>
#include <math.h>

#define PI4F 0.78539816339744830962f

// ---------------- Kernel 1: global average pool ----------------
__global__ void k_pool(const float* __restrict__ x, float* __restrict__ pooled) {
    int bc = blockIdx.x;
    const float* p = x + (size_t)bc * 16384;
    float s = 0.f;
    for (int j = threadIdx.x; j < 16384; j += 256) s += p[j];
    for (int off = 32; off > 0; off >>= 1) s += __shfl_xor(s, off, 64);
    __shared__ float red[4];
    int wave = threadIdx.x >> 6;
    if ((threadIdx.x & 63) == 0) red[wave] = s;
    __syncthreads();
    if (threadIdx.x == 0) {
        float t = red[0] + red[1] + red[2] + red[3];
        pooled[bc] = t * (1.0f / 16384.0f);
    }
}

// ---------------- Kernel 2: small MLPs -> angles, mod ----------------
__global__ void k_mlp(const float* __restrict__ pooled,
                      const float* __restrict__ aw1, const float* __restrict__ ab1,
                      const float* __restrict__ aw2, const float* __restrict__ ab2,
                      const float* __restrict__ mw1, const float* __restrict__ mb1,
                      const float* __restrict__ mw2, const float* __restrict__ mb2,
                      float* __restrict__ angles, float* __restrict__ mod) {
    int i = blockIdx.x >> 3, b = blockIdx.x & 7;
    int t = threadIdx.x;
    __shared__ float sp[64], sha[16], shm[16];
    sp[t] = pooled[b * 64 + t];
    __syncthreads();
    if (t < 16) {
        float sa = ab1[i * 16 + t], sm = mb1[i * 16 + t];
        const float* wa = aw1 + ((size_t)i * 16 + t) * 64;
        const float* wm = mw1 + ((size_t)i * 16 + t) * 64;
        for (int c = 0; c < 64; ++c) { sa = fmaf(wa[c], sp[c], sa); sm = fmaf(wm[c], sp[c], sm); }
        sha[t] = fmaxf(sa, 0.f);
        shm[t] = fmaxf(sm, 0.f);
    }
    __syncthreads();
    if (t < 8) {
        float s = ab2[i * 8 + t];
        const float* w = aw2 + ((size_t)i * 8 + t) * 16;
        for (int j = 0; j < 16; ++j) s = fmaf(w[j], sha[j], s);
        angles[i * 64 + b * 8 + t] = tanhf(s) * PI4F;
    }
    {
        float s = mb2[i * 64 + t];
        const float* w = mw2 + ((size_t)i * 64 + t) * 16;
        for (int j = 0; j < 16; ++j) s = fmaf(w[j], shm[j], s);
        mod[i * 512 + b * 64 + t] = 1.f / (1.f + expf(-s));
    }
}

// ---------------- Kernel 3: rotate base kernels ----------------
__global__ void k_rot(const float* __restrict__ bk, const float* __restrict__ angles,
                      float* __restrict__ rot) {
    int blk = blockIdx.x;
    int g = blk & 7, b = (blk >> 3) & 7, i = blk >> 6;
    float ang = angles[i * 64 + b * 8 + g];
    float st, ct;
    sincosf(ang, &st, &ct);
    int t = threadIdx.x;
    int co = t >> 3, ci = t & 7;
    const float* K = bk + ((((size_t)i * 8 + g) * 8 + co) * 8 + ci) * 9;
    float* R = rot + ((((size_t)i * 8 + b) * 8 + g) * 64 + t) * 9;
    for (int p = 0; p < 9; ++p) {
        int ky = p / 3, kx = p % 3;
        float xx = (float)kx - 1.f, yy = (float)ky - 1.f;
        float xr = xx * ct + yy * st + 1.f;
        float yr = -xx * st + yy * ct + 1.f;
        float x0 = fminf(fmaxf(floorf(xr), 0.f), 1.f);
        float y0 = fminf(fmaxf(floorf(yr), 0.f), 1.f);
        float x1 = x0 + 1.f, y1 = y0 + 1.f;
        float w00 = (x1 - xr) * (y1 - yr);
        float w01 = (x1 - xr) * (yr - y0);
        float w10 = (xr - x0) * (y1 - yr);
        float w11 = (xr - x0) * (yr - y0);
        int x0i = (int)x0, y0i = (int)y0;
        float v = w00 * K[y0i * 3 + x0i] + w01 * K[(y0i + 1) * 3 + x0i]
                + w10 * K[y0i * 3 + x0i + 1] + w11 * K[(y0i + 1) * 3 + x0i + 1];
        R[p] = v;
    }
}

// ---------------- Kernel 4: tiled conv, all 4 branches per block ----------------
// grid (16, 64) = (tile, b*8+g); block 256.
__global__ void __launch_bounds__(256) k_conv(const float* __restrict__ x,
                       const float* __restrict__ rot, const float* __restrict__ mod,
                       float* __restrict__ bf) {
    __shared__ float s_in[8 * 34 * 34];

    int bg = blockIdx.y;
    int b = bg >> 3, g = bg & 7;
    int tile_h0 = (blockIdx.x >> 2) * 32;
    int tile_w0 = (blockIdx.x & 3) * 32;
    int tid = threadIdx.x;

    const float* xg = x + ((size_t)b * 64 + (size_t)g * 8) * 16384;
    for (int idx = tid; idx < 8 * 1156; idx += 256) {
        int ci = idx / 1156;
        int rem = idx - ci * 1156;
        int r = rem / 34;
        int c = rem - r * 34;
        int gh = tile_h0 + r - 1;
        int gw = tile_w0 + c - 1;
        float v = 0.f;
        if (gh >= 0 && gh < 128 && gw >= 0 && gw < 128)
            v = xg[(size_t)ci * 16384 + gh * 128 + gw];
        s_in[idx] = v;
    }
    __syncthreads();

    int lc = tid & 31;
    int lr0 = (tid >> 5) * 4;

#pragma unroll 1
    for (int i = 0; i < 4; ++i) {
        const float* wbase = rot + ((size_t)(i * 8 + b) * 8 + g) * 576;  // uniform -> s_load

        float acc[8][4];
#pragma unroll
        for (int co = 0; co < 8; ++co)
#pragma unroll
            for (int p = 0; p < 4; ++p) acc[co][p] = 0.f;

#pragma unroll
        for (int ci = 0; ci < 8; ++ci) {
            float v[6][3];
            int base = ci * 1156 + lr0 * 34 + lc;
#pragma unroll
            for (int r = 0; r < 6; ++r)
#pragma unroll
                for (int c = 0; c < 3; ++c)
                    v[r][c] = s_in[base + r * 34 + c];

#pragma unroll
            for (int co = 0; co < 8; ++co) {
                const float* wp = wbase + (co * 8 + ci) * 9;
#pragma unroll
                for (int ky = 0; ky < 3; ++ky)
#pragma unroll
                    for (int kx = 0; kx < 3; ++kx) {
                        float wv = wp[ky * 3 + kx];
#pragma unroll
                        for (int p = 0; p < 4; ++p)
                            acc[co][p] = fmaf(wv, v[p + ky][kx], acc[co][p]);
                    }
            }
        }

#pragma unroll
        for (int co = 0; co < 8; ++co) {
            int c = g * 8 + co;
            float mv = mod[i * 512 + b * 64 + c];
            float* op = bf + ((size_t)(i * 8 + b) * 64 + c) * 16384;
#pragma unroll
            for (int p = 0; p < 4; ++p) {
                int gh = tile_h0 + lr0 + p;
                op[gh * 128 + tile_w0 + lc] = acc[co][p] * mv;
            }
        }
    }
}

// ---------------- Kernel 5 (v4): fused epilogue, SGPR weights via loop-swap ----------------
// thread-per-pixel; grid 512 x 256. No LDS, no ws prep, no aliasing.
__global__ void __launch_bounds__(256) k_mega(
    const float* __restrict__ x, const float* __restrict__ bfeat,
    const float* __restrict__ roi,
    const float* __restrict__ w1,
    const float* __restrict__ bnw, const float* __restrict__ bnb,
    const float* __restrict__ bnm, const float* __restrict__ bnv,
    const float* __restrict__ w2, const float* __restrict__ b2,
    const float* __restrict__ ew1,
    const float* __restrict__ ebnw, const float* __restrict__ ebnb,
    const float* __restrict__ ebnm, const float* __restrict__ ebnv,
    const float* __restrict__ ew2, const float* __restrict__ eb2,
    float* __restrict__ out) {

    int tid = threadIdx.x;
    int p = blockIdx.x * 256 + tid;
    int b = p >> 14;
    int hw = p & 16383;
    int h = hw >> 7, w = hw & 127;

    const float* fb = bfeat + ((size_t)b * 64) * 16384 + hw;

    // ---- phase 1: y = dir_w1 @ feats_cat ----
    // Loop-swap: stage 64 features in VGPRs, weight rows are block-uniform
    // and consecutive -> s_load_dwordx16; inner loop is v_fma (SGPR, VGPR).
    float y[64];
#pragma unroll
    for (int o = 0; o < 64; ++o) y[o] = 0.f;
#pragma unroll 1
    for (int ch = 0; ch < 4; ++ch) {
        const float* fbi = fb + (size_t)ch * 512 * 16384;
        float f[64];
#pragma unroll
        for (int j = 0; j < 64; ++j) f[j] = fbi[(size_t)j * 16384];
#pragma unroll 2
        for (int o = 0; o < 64; ++o) {
            const float* wr = w1 + o * 256 + ch * 64;   // block-uniform -> SGPR
            float s = y[o];
#pragma unroll
            for (int j = 0; j < 64; ++j) s = fmaf(wr[j], f[j], s);
            y[o] = s;
        }
    }
    // dir BN (inline fold) + relu
#pragma unroll 4
    for (int o = 0; o < 64; ++o) {
        float sc = bnw[o] * rsqrtf(bnv[o] + 1e-5f);      // uniform
        float sh = bnb[o] - bnm[o] * sc;
        y[o] = fmaxf(fmaf(y[o], sc, sh), 0.f);
    }

    // ---- phase 2: logits + softmax ----
    float lg[4];
#pragma unroll
    for (int k = 0; k < 4; ++k) {
        float s = b2[k];
        const float* wr = w2 + k * 64;                   // uniform
#pragma unroll
        for (int o = 0; o < 64; ++o) s = fmaf(wr[o], y[o], s);
        lg[k] = s;
    }
    float mx = fmaxf(fmaxf(lg[0], lg[1]), fmaxf(lg[2], lg[3]));
    float e0 = expf(lg[0] - mx), e1s = expf(lg[1] - mx), e2s = expf(lg[2] - mx), e3s = expf(lg[3] - mx);
    float inv = 1.f / (e0 + e1s + e2s + e3s);
    float a0 = e0 * inv, a1 = e1s * inv, a2 = e2s * inv, a3 = e3s * inv;

    // ---- phase 3: roi bilinear (align_corners) ----
    float ysv = (float)h * (63.f / 127.f);
    float y0f = fminf(floorf(ysv), 62.f);
    float wy = ysv - y0f;
    float xsv = (float)w * (63.f / 127.f);
    float x0f = fminf(floorf(xsv), 62.f);
    float wx = xsv - x0f;
    int y0i = (int)y0f, x0i = (int)x0f;
    const float* rb = roi + (size_t)b * 4096;
    float r00 = rb[y0i * 64 + x0i], r01 = rb[y0i * 64 + x0i + 1];
    float r10 = rb[(y0i + 1) * 64 + x0i], r11 = rb[(y0i + 1) * 64 + x0i + 1];
    float rv = r00 * (1.f - wy) * (1.f - wx) + r01 * (1.f - wy) * wx
             + r10 * wy * (1.f - wx) + r11 * wy * wx;

    // ---- phase 4: fused = sum_i bf_i * attn_i, scaled by roi ----
    float f[64];
#pragma unroll 8
    for (int cc = 0; cc < 64; ++cc) {
        const float* pp = fb + (size_t)cc * 16384;
        float s = a0 * pp[0]
                + a1 * pp[(size_t)512 * 16384]
                + a2 * pp[(size_t)1024 * 16384]
                + a3 * pp[(size_t)1536 * 16384];
        f[cc] = s * rv;
    }

    // ---- phase 5: edge MLP layer 1 (SGPR weights, inline BN) + relu ----
    float eh[32];
#pragma unroll 2
    for (int o = 0; o < 32; ++o) {
        float s = 0.f;
        const float* wr = ew1 + o * 64;                  // uniform
#pragma unroll
        for (int c = 0; c < 64; ++c) s = fmaf(wr[c], f[c], s);
        float sc = ebnw[o] * rsqrtf(ebnv[o] + 1e-5f);
        float sh = ebnb[o] - ebnm[o] * sc;
        eh[o] = fmaxf(fmaf(s, sc, sh), 0.f);
    }

    // ---- phase 6: e2 = sigmoid(ew2 @ eh + b), out = x*(1+e2) ----
    const float* xp = x + ((size_t)b * 64) * 16384 + hw;
    float* op = out + ((size_t)b * 64) * 16384 + hw;
#pragma unroll 2
    for (int cc = 0; cc < 64; ++cc) {
        float s = eb2[cc];
        const float* wr = ew2 + cc * 32;                 // uniform
#pragma unroll
        for (int c = 0; c < 32; ++c) s = fmaf(wr[c], eh[c], s);
        float sg = 1.f / (1.f + expf(-s));
        float xv = xp[(size_t)cc * 16384];
        op[(size_t)cc * 16384] = xv + xv * sg;
    }
}

extern "C" void kernel_launch(void* const* d_in, const int* in_sizes, int n_in,
                              void* d_out, int out_size, void* d_ws, size_t ws_size,
                              hipStream_t stream) {
    const float* x    = (const float*)d_in[0];
    const float* roi  = (const float*)d_in[1];
    const float* bk   = (const float*)d_in[2];
    const float* aw1  = (const float*)d_in[3];
    const float* ab1  = (const float*)d_in[4];
    const float* aw2  = (const float*)d_in[5];
    const float* ab2  = (const float*)d_in[6];
    const float* mw1  = (const float*)d_in[7];
    const float* mb1  = (const float*)d_in[8];
    const float* mw2  = (const float*)d_in[9];
    const float* mb2  = (const float*)d_in[10];
    const float* w1   = (const float*)d_in[11];
    const float* bnw  = (const float*)d_in[12];
    const float* bnb  = (const float*)d_in[13];
    const float* bnm  = (const float*)d_in[14];
    const float* bnv  = (const float*)d_in[15];
    const float* w2   = (const float*)d_in[16];
    const float* b2   = (const float*)d_in[17];
    const float* ew1  = (const float*)d_in[18];
    const float* ebnw = (const float*)d_in[19];
    const float* ebnb = (const float*)d_in[20];
    const float* ebnm = (const float*)d_in[21];
    const float* ebnv = (const float*)d_in[22];
    const float* ew2  = (const float*)d_in[23];
    const float* eb2  = (const float*)d_in[24];

    float* ws     = (float*)d_ws;
    float* pooled = ws;              // 512
    float* angles = ws + 512;        // 256
    float* mod    = ws + 768;        // 2048
    float* rot    = ws + 2816;       // 147456
    float* bfeat  = ws + 150272;     // 4*8*64*16384

    k_pool<<<512, 256, 0, stream>>>(x, pooled);
    k_mlp<<<32, 64, 0, stream>>>(pooled, aw1, ab1, aw2, ab2, mw1, mb1, mw2, mb2, angles, mod);
    k_rot<<<256, 64, 0, stream>>>(bk, angles, rot);
    k_conv<<<dim3(16, 64), 256, 0, stream>>>(x, rot, mod, bfeat);
    k_mega<<<512, 256, 0, stream>>>(x, bfeat, roi, w1,
                                    bnw, bnb, bnm, bnv, w2, b2,
                                    ew1, ebnw, ebnb, ebnm, ebnv, ew2, eb2,
                                    (float*)d_out);
}

// Round 5
// 449.030 us; speedup vs baseline: 1.1912x; 1.1912x over previous
//
#include <hip/hip_runtime.h>
#include <hip/hip_bf16.h>
#include <math.h>

#define PI4F 0.78539816339744830962f

// ---------------- Kernel 1: global average pool ----------------
__global__ void k_pool(const float* __restrict__ x, float* __restrict__ pooled) {
    int bc = blockIdx.x;
    const float* p = x + (size_t)bc * 16384;
    float s = 0.f;
    for (int j = threadIdx.x; j < 16384; j += 256) s += p[j];
    for (int off = 32; off > 0; off >>= 1) s += __shfl_xor(s, off, 64);
    __shared__ float red[4];
    int wave = threadIdx.x >> 6;
    if ((threadIdx.x & 63) == 0) red[wave] = s;
    __syncthreads();
    if (threadIdx.x == 0) {
        float t = red[0] + red[1] + red[2] + red[3];
        pooled[bc] = t * (1.0f / 16384.0f);
    }
}

// ---------------- Kernel 2: small MLPs -> angles, mod ----------------
__global__ void k_mlp(const float* __restrict__ pooled,
                      const float* __restrict__ aw1, const float* __restrict__ ab1,
                      const float* __restrict__ aw2, const float* __restrict__ ab2,
                      const float* __restrict__ mw1, const float* __restrict__ mb1,
                      const float* __restrict__ mw2, const float* __restrict__ mb2,
                      float* __restrict__ angles, float* __restrict__ mod) {
    int i = blockIdx.x >> 3, b = blockIdx.x & 7;
    int t = threadIdx.x;
    __shared__ float sp[64], sha[16], shm[16];
    sp[t] = pooled[b * 64 + t];
    __syncthreads();
    if (t < 16) {
        float sa = ab1[i * 16 + t], sm = mb1[i * 16 + t];
        const float* wa = aw1 + ((size_t)i * 16 + t) * 64;
        const float* wm = mw1 + ((size_t)i * 16 + t) * 64;
        for (int c = 0; c < 64; ++c) { sa = fmaf(wa[c], sp[c], sa); sm = fmaf(wm[c], sp[c], sm); }
        sha[t] = fmaxf(sa, 0.f);
        shm[t] = fmaxf(sm, 0.f);
    }
    __syncthreads();
    if (t < 8) {
        float s = ab2[i * 8 + t];
        const float* w = aw2 + ((size_t)i * 8 + t) * 16;
        for (int j = 0; j < 16; ++j) s = fmaf(w[j], sha[j], s);
        angles[i * 64 + b * 8 + t] = tanhf(s) * PI4F;
    }
    {
        float s = mb2[i * 64 + t];
        const float* w = mw2 + ((size_t)i * 64 + t) * 16;
        for (int j = 0; j < 16; ++j) s = fmaf(w[j], shm[j], s);
        mod[i * 512 + b * 64 + t] = 1.f / (1.f + expf(-s));
    }
}

// ---------------- Kernel 3: rotate base kernels ----------------
__global__ void k_rot(const float* __restrict__ bk, const float* __restrict__ angles,
                      float* __restrict__ rot) {
    int blk = blockIdx.x;
    int g = blk & 7, b = (blk >> 3) & 7, i = blk >> 6;
    float ang = angles[i * 64 + b * 8 + g];
    float st, ct;
    sincosf(ang, &st, &ct);
    int t = threadIdx.x;
    int co = t >> 3, ci = t & 7;
    const float* K = bk + ((((size_t)i * 8 + g) * 8 + co) * 8 + ci) * 9;
    float* R = rot + ((((size_t)i * 8 + b) * 8 + g) * 64 + t) * 9;
    for (int p = 0; p < 9; ++p) {
        int ky = p / 3, kx = p % 3;
        float xx = (float)kx - 1.f, yy = (float)ky - 1.f;
        float xr = xx * ct + yy * st + 1.f;
        float yr = -xx * st + yy * ct + 1.f;
        float x0 = fminf(fmaxf(floorf(xr), 0.f), 1.f);
        float y0 = fminf(fmaxf(floorf(yr), 0.f), 1.f);
        float x1 = x0 + 1.f, y1 = y0 + 1.f;
        float w00 = (x1 - xr) * (y1 - yr);
        float w01 = (x1 - xr) * (yr - y0);
        float w10 = (xr - x0) * (y1 - yr);
        float w11 = (xr - x0) * (yr - y0);
        int x0i = (int)x0, y0i = (int)y0;
        float v = w00 * K[y0i * 3 + x0i] + w01 * K[(y0i + 1) * 3 + x0i]
                + w10 * K[y0i * 3 + x0i + 1] + w11 * K[(y0i + 1) * 3 + x0i + 1];
        R[p] = v;
    }
}

// ---------------- Kernel 3.5: prep (w1 transpose + dir-BN scale fold) ----------------
// Writes DEDICATED ws regions (no aliasing with rot/bfeat). 1 block, 256 threads.
__global__ void k_prep(const float* __restrict__ w1,
                       const float* __restrict__ bnw, const float* __restrict__ bnb,
                       const float* __restrict__ bnm, const float* __restrict__ bnv,
                       float* __restrict__ w1ts, float* __restrict__ dsh) {
    int tid = threadIdx.x;
    __shared__ float sc[64];
    if (tid < 64) {
        float s = bnw[tid] * rsqrtf(bnv[tid] + 1e-5f);
        sc[tid] = s;
        dsh[tid] = bnb[tid] - bnm[tid] * s;
    }
    __syncthreads();
    for (int q = tid; q < 16384; q += 256) {
        int o = q >> 8, k = q & 255;
        w1ts[k * 64 + o] = w1[q] * sc[o];    // scale folded into weights
    }
}

// ---------------- Kernel 4 (v4): tiled conv, 2 branches per LDS pass, bf16 out ----------------
// grid (16, 64) = (tile, b*8+g); block 256.
__global__ void __launch_bounds__(256) k_conv(const float* __restrict__ x,
                       const float* __restrict__ rot, const float* __restrict__ mod,
                       __hip_bfloat16* __restrict__ bf) {
    __shared__ float s_in[8 * 34 * 34];

    int bg = blockIdx.y;
    int b = bg >> 3, g = bg & 7;
    int tile_h0 = (blockIdx.x >> 2) * 32;
    int tile_w0 = (blockIdx.x & 3) * 32;
    int tid = threadIdx.x;

    const float* xg = x + ((size_t)b * 64 + (size_t)g * 8) * 16384;
    for (int idx = tid; idx < 8 * 1156; idx += 256) {
        int ci = idx / 1156;
        int rem = idx - ci * 1156;
        int r = rem / 34;
        int c = rem - r * 34;
        int gh = tile_h0 + r - 1;
        int gw = tile_w0 + c - 1;
        float v = 0.f;
        if (gh >= 0 && gh < 128 && gw >= 0 && gw < 128)
            v = xg[(size_t)ci * 16384 + gh * 128 + gw];
        s_in[idx] = v;
    }
    __syncthreads();

    int lc = tid & 31;
    int lr0 = (tid >> 5) * 4;

#pragma unroll 1
    for (int ii = 0; ii < 4; ii += 2) {          // two branches per LDS read pass
        float acc[2][8][4];
#pragma unroll
        for (int q = 0; q < 2; ++q)
#pragma unroll
            for (int co = 0; co < 8; ++co)
#pragma unroll
                for (int p = 0; p < 4; ++p) acc[q][co][p] = 0.f;

#pragma unroll
        for (int ci = 0; ci < 8; ++ci) {
            float v[6][3];
            int base = ci * 1156 + lr0 * 34 + lc;
#pragma unroll
            for (int r = 0; r < 6; ++r)
#pragma unroll
                for (int c = 0; c < 3; ++c)
                    v[r][c] = s_in[base + r * 34 + c];

#pragma unroll
            for (int q = 0; q < 2; ++q) {
                const float* wbase = rot + ((size_t)((ii + q) * 8 + b) * 8 + g) * 576;  // uniform
#pragma unroll
                for (int co = 0; co < 8; ++co) {
                    const float* wp = wbase + (co * 8 + ci) * 9;
#pragma unroll
                    for (int ky = 0; ky < 3; ++ky)
#pragma unroll
                        for (int kx = 0; kx < 3; ++kx) {
                            float wv = wp[ky * 3 + kx];
#pragma unroll
                            for (int p = 0; p < 4; ++p)
                                acc[q][co][p] = fmaf(wv, v[p + ky][kx], acc[q][co][p]);
                        }
                }
            }
        }

#pragma unroll
        for (int q = 0; q < 2; ++q) {
            int i = ii + q;
#pragma unroll
            for (int co = 0; co < 8; ++co) {
                int c = g * 8 + co;
                float mv = mod[i * 512 + b * 64 + c];
                __hip_bfloat16* op = bf + ((size_t)(i * 8 + b) * 64 + c) * 16384;
#pragma unroll
                for (int p = 0; p < 4; ++p) {
                    int gh = tile_h0 + lr0 + p;
                    op[gh * 128 + tile_w0 + lc] = __float2bfloat16(acc[q][co][p] * mv);
                }
            }
        }
    }
}

// ---------------- Kernel 5 (v5): fused epilogue, SGPR weights, all-static indexing ----------------
// thread-per-pixel; grid 512 x 256.
__global__ void __launch_bounds__(256) k_mega(
    const float* __restrict__ x, const __hip_bfloat16* __restrict__ bfeat,
    const float* __restrict__ roi,
    const float* __restrict__ w1ts, const float* __restrict__ dsh,
    const float* __restrict__ w2, const float* __restrict__ b2,
    const float* __restrict__ ew1,
    const float* __restrict__ ebnw, const float* __restrict__ ebnb,
    const float* __restrict__ ebnm, const float* __restrict__ ebnv,
    const float* __restrict__ ew2, const float* __restrict__ eb2,
    float* __restrict__ out) {

    int tid = threadIdx.x;
    int p = blockIdx.x * 256 + tid;
    int b = p >> 14;
    int hw = p & 16383;
    int h = hw >> 7, w = hw & 127;

    const __hip_bfloat16* fb = bfeat + ((size_t)b * 64) * 16384 + hw;

    // ---- phase 1: y = (dir_w1*sc) @ feats_cat + dsh ----
    // j runtime, o FULLY unrolled (y[o] static). wr consecutive -> s_load_dwordx16.
    float y[64];
#pragma unroll
    for (int o = 0; o < 64; ++o) y[o] = dsh[o];
#pragma unroll 1
    for (int ch = 0; ch < 4; ++ch) {
        const __hip_bfloat16* fbi = fb + (size_t)ch * 512 * 16384;
        const float* wch = w1ts + ch * 4096;
#pragma unroll 1
        for (int j = 0; j < 64; ++j) {
            float fv = __bfloat162float(fbi[(size_t)j * 16384]);
            const float* wr = wch + j * 64;              // block-uniform -> SGPR
#pragma unroll
            for (int o = 0; o < 64; ++o) y[o] = fmaf(wr[o], fv, y[o]);
        }
    }
#pragma unroll
    for (int o = 0; o < 64; ++o) y[o] = fmaxf(y[o], 0.f);

    // ---- phase 2: logits + softmax (fully unrolled) ----
    float lg[4];
#pragma unroll
    for (int k = 0; k < 4; ++k) {
        float s = b2[k];
        const float* wr = w2 + k * 64;                   // uniform
#pragma unroll
        for (int o = 0; o < 64; ++o) s = fmaf(wr[o], y[o], s);
        lg[k] = s;
    }
    float mx = fmaxf(fmaxf(lg[0], lg[1]), fmaxf(lg[2], lg[3]));
    float e0 = expf(lg[0] - mx), e1s = expf(lg[1] - mx), e2s = expf(lg[2] - mx), e3s = expf(lg[3] - mx);
    float inv = 1.f / (e0 + e1s + e2s + e3s);
    float a0 = e0 * inv, a1 = e1s * inv, a2 = e2s * inv, a3 = e3s * inv;

    // ---- phase 3: roi bilinear (align_corners) ----
    float ysv = (float)h * (63.f / 127.f);
    float y0f = fminf(floorf(ysv), 62.f);
    float wy = ysv - y0f;
    float xsv = (float)w * (63.f / 127.f);
    float x0f = fminf(floorf(xsv), 62.f);
    float wx = xsv - x0f;
    int y0i = (int)y0f, x0i = (int)x0f;
    const float* rb = roi + (size_t)b * 4096;
    float r00 = rb[y0i * 64 + x0i], r01 = rb[y0i * 64 + x0i + 1];
    float r10 = rb[(y0i + 1) * 64 + x0i], r11 = rb[(y0i + 1) * 64 + x0i + 1];
    float rv = r00 * (1.f - wy) * (1.f - wx) + r01 * (1.f - wy) * wx
             + r10 * wy * (1.f - wx) + r11 * wy * wx;

    // ---- phase 4: fused = sum_i bf_i * attn_i, scaled by roi (fully unrolled) ----
    float f[64];
#pragma unroll
    for (int cc = 0; cc < 64; ++cc) {
        const __hip_bfloat16* pp = fb + (size_t)cc * 16384;
        float s = a0 * __bfloat162float(pp[0])
                + a1 * __bfloat162float(pp[(size_t)512 * 16384])
                + a2 * __bfloat162float(pp[(size_t)1024 * 16384])
                + a3 * __bfloat162float(pp[(size_t)1536 * 16384]);
        f[cc] = s * rv;
    }

    // ---- phase 5: edge MLP layer 1 (fully unrolled, inline BN) + relu ----
    float eh[32];
#pragma unroll
    for (int o = 0; o < 32; ++o) {
        float s = 0.f;
        const float* wr = ew1 + o * 64;                  // uniform, imm offsets
#pragma unroll
        for (int c = 0; c < 64; ++c) s = fmaf(wr[c], f[c], s);
        float sc = ebnw[o] * rsqrtf(ebnv[o] + 1e-5f);
        float sh = ebnb[o] - ebnm[o] * sc;
        eh[o] = fmaxf(fmaf(s, sc, sh), 0.f);
    }

    // ---- phase 6: e2 = sigmoid(ew2 @ eh + b), out = x*(1+e2) ----
    // cc runtime (nothing runtime-indexed per-thread), inner c unrolled.
    const float* xp = x + ((size_t)b * 64) * 16384 + hw;
    float* op = out + ((size_t)b * 64) * 16384 + hw;
#pragma unroll 1
    for (int cc = 0; cc < 64; ++cc) {
        float s = eb2[cc];
        const float* wr = ew2 + cc * 32;                 // uniform -> s_load
#pragma unroll
        for (int c = 0; c < 32; ++c) s = fmaf(wr[c], eh[c], s);
        float sg = 1.f / (1.f + expf(-s));
        float xv = xp[(size_t)cc * 16384];
        op[(size_t)cc * 16384] = xv + xv * sg;
    }
}

extern "C" void kernel_launch(void* const* d_in, const int* in_sizes, int n_in,
                              void* d_out, int out_size, void* d_ws, size_t ws_size,
                              hipStream_t stream) {
    const float* x    = (const float*)d_in[0];
    const float* roi  = (const float*)d_in[1];
    const float* bk   = (const float*)d_in[2];
    const float* aw1  = (const float*)d_in[3];
    const float* ab1  = (const float*)d_in[4];
    const float* aw2  = (const float*)d_in[5];
    const float* ab2  = (const float*)d_in[6];
    const float* mw1  = (const float*)d_in[7];
    const float* mb1  = (const float*)d_in[8];
    const float* mw2  = (const float*)d_in[9];
    const float* mb2  = (const float*)d_in[10];
    const float* w1   = (const float*)d_in[11];
    const float* bnw  = (const float*)d_in[12];
    const float* bnb  = (const float*)d_in[13];
    const float* bnm  = (const float*)d_in[14];
    const float* bnv  = (const float*)d_in[15];
    const float* w2   = (const float*)d_in[16];
    const float* b2   = (const float*)d_in[17];
    const float* ew1  = (const float*)d_in[18];
    const float* ebnw = (const float*)d_in[19];
    const float* ebnb = (const float*)d_in[20];
    const float* ebnm = (const float*)d_in[21];
    const float* ebnv = (const float*)d_in[22];
    const float* ew2  = (const float*)d_in[23];
    const float* eb2  = (const float*)d_in[24];

    float* ws     = (float*)d_ws;
    float* pooled = ws;                    // 512
    float* angles = ws + 512;              // 256
    float* mod    = ws + 768;              // 2048
    float* rot    = ws + 2816;             // 147456
    float* w1ts   = ws + 150272;           // 16384   (dedicated - no aliasing)
    float* dsh    = ws + 166656;           // 64
    __hip_bfloat16* bfeat = (__hip_bfloat16*)(ws + 166720);  // 33554432 bf16 = 64 MB

    k_prep<<<1, 256, 0, stream>>>(w1, bnw, bnb, bnm, bnv, w1ts, dsh);
    k_pool<<<512, 256, 0, stream>>>(x, pooled);
    k_mlp<<<32, 64, 0, stream>>>(pooled, aw1, ab1, aw2, ab2, mw1, mb1, mw2, mb2, angles, mod);
    k_rot<<<256, 64, 0, stream>>>(bk, angles, rot);
    k_conv<<<dim3(16, 64), 256, 0, stream>>>(x, rot, mod, bfeat);
    k_mega<<<512, 256, 0, stream>>>(x, bfeat, roi, w1ts, dsh, w2, b2,
                                    ew1, ebnw, ebnb, ebnm, ebnv, ew2, eb2,
                                    (float*)d_out);
}

// Round 6
// 300.634 us; speedup vs baseline: 1.7791x; 1.4936x over previous
//
#include <hip/hip_runtime.h>
#include <hip/hip_bf16.h>
#include <math.h>

#define PI4F 0.78539816339744830962f

// ---------------- Kernel 1: global average pool ----------------
__global__ void k_pool(const float* __restrict__ x, float* __restrict__ pooled) {
    int bc = blockIdx.x;
    const float* p = x + (size_t)bc * 16384;
    float s = 0.f;
    for (int j = threadIdx.x; j < 16384; j += 256) s += p[j];
    for (int off = 32; off > 0; off >>= 1) s += __shfl_xor(s, off, 64);
    __shared__ float red[4];
    int wave = threadIdx.x >> 6;
    if ((threadIdx.x & 63) == 0) red[wave] = s;
    __syncthreads();
    if (threadIdx.x == 0) {
        float t = red[0] + red[1] + red[2] + red[3];
        pooled[bc] = t * (1.0f / 16384.0f);
    }
}

// ---------------- Kernel 2: small MLPs -> angles, mod ----------------
__global__ void k_mlp(const float* __restrict__ pooled,
                      const float* __restrict__ aw1, const float* __restrict__ ab1,
                      const float* __restrict__ aw2, const float* __restrict__ ab2,
                      const float* __restrict__ mw1, const float* __restrict__ mb1,
                      const float* __restrict__ mw2, const float* __restrict__ mb2,
                      float* __restrict__ angles, float* __restrict__ mod) {
    int i = blockIdx.x >> 3, b = blockIdx.x & 7;
    int t = threadIdx.x;
    __shared__ float sp[64], sha[16], shm[16];
    sp[t] = pooled[b * 64 + t];
    __syncthreads();
    if (t < 16) {
        float sa = ab1[i * 16 + t], sm = mb1[i * 16 + t];
        const float* wa = aw1 + ((size_t)i * 16 + t) * 64;
        const float* wm = mw1 + ((size_t)i * 16 + t) * 64;
        for (int c = 0; c < 64; ++c) { sa = fmaf(wa[c], sp[c], sa); sm = fmaf(wm[c], sp[c], sm); }
        sha[t] = fmaxf(sa, 0.f);
        shm[t] = fmaxf(sm, 0.f);
    }
    __syncthreads();
    if (t < 8) {
        float s = ab2[i * 8 + t];
        const float* w = aw2 + ((size_t)i * 8 + t) * 16;
        for (int j = 0; j < 16; ++j) s = fmaf(w[j], sha[j], s);
        angles[i * 64 + b * 8 + t] = tanhf(s) * PI4F;
    }
    {
        float s = mb2[i * 64 + t];
        const float* w = mw2 + ((size_t)i * 64 + t) * 16;
        for (int j = 0; j < 16; ++j) s = fmaf(w[j], shm[j], s);
        mod[i * 512 + b * 64 + t] = 1.f / (1.f + expf(-s));
    }
}

// ---------------- Kernel 3: rotate base kernels ----------------
__global__ void k_rot(const float* __restrict__ bk, const float* __restrict__ angles,
                      float* __restrict__ rot) {
    int blk = blockIdx.x;
    int g = blk & 7, b = (blk >> 3) & 7, i = blk >> 6;
    float ang = angles[i * 64 + b * 8 + g];
    float st, ct;
    sincosf(ang, &st, &ct);
    int t = threadIdx.x;
    int co = t >> 3, ci = t & 7;
    const float* K = bk + ((((size_t)i * 8 + g) * 8 + co) * 8 + ci) * 9;
    float* R = rot + ((((size_t)i * 8 + b) * 8 + g) * 64 + t) * 9;
    for (int p = 0; p < 9; ++p) {
        int ky = p / 3, kx = p % 3;
        float xx = (float)kx - 1.f, yy = (float)ky - 1.f;
        float xr = xx * ct + yy * st + 1.f;
        float yr = -xx * st + yy * ct + 1.f;
        float x0 = fminf(fmaxf(floorf(xr), 0.f), 1.f);
        float y0 = fminf(fmaxf(floorf(yr), 0.f), 1.f);
        float x1 = x0 + 1.f, y1 = y0 + 1.f;
        float w00 = (x1 - xr) * (y1 - yr);
        float w01 = (x1 - xr) * (yr - y0);
        float w10 = (xr - x0) * (y1 - yr);
        float w11 = (xr - x0) * (yr - y0);
        int x0i = (int)x0, y0i = (int)y0;
        float v = w00 * K[y0i * 3 + x0i] + w01 * K[(y0i + 1) * 3 + x0i]
                + w10 * K[y0i * 3 + x0i + 1] + w11 * K[(y0i + 1) * 3 + x0i + 1];
        R[p] = v;
    }
}

// ---------------- Kernel 3.5: prep (w1 transpose + dir-BN scale fold) ----------------
// Writes DEDICATED ws regions (no aliasing). 1 block, 256 threads.
__global__ void k_prep(const float* __restrict__ w1,
                       const float* __restrict__ bnw, const float* __restrict__ bnb,
                       const float* __restrict__ bnm, const float* __restrict__ bnv,
                       float* __restrict__ w1ts, float* __restrict__ dsh) {
    int tid = threadIdx.x;
    __shared__ float sc[64];
    if (tid < 64) {
        float s = bnw[tid] * rsqrtf(bnv[tid] + 1e-5f);
        sc[tid] = s;
        dsh[tid] = bnb[tid] - bnm[tid] * s;
    }
    __syncthreads();
    for (int q = tid; q < 16384; q += 256) {
        int o = q >> 8, k = q & 255;
        w1ts[k * 64 + o] = w1[q] * sc[o];    // scale folded into weights
    }
}

// ---------------- Kernel 4 (v5): tiled conv, 1 branch per pass, bf16 out ----------------
// grid (16, 64) = (tile, b*8+g); block 256. x-tile staged ONCE for 4 branches.
__global__ void __launch_bounds__(256) k_conv(const float* __restrict__ x,
                       const float* __restrict__ rot, const float* __restrict__ mod,
                       __hip_bfloat16* __restrict__ bf) {
    __shared__ float s_in[8 * 34 * 34];

    int bg = blockIdx.y;
    int b = bg >> 3, g = bg & 7;
    int tile_h0 = (blockIdx.x >> 2) * 32;
    int tile_w0 = (blockIdx.x & 3) * 32;
    int tid = threadIdx.x;

    const float* xg = x + ((size_t)b * 64 + (size_t)g * 8) * 16384;
    for (int idx = tid; idx < 8 * 1156; idx += 256) {
        int ci = idx / 1156;
        int rem = idx - ci * 1156;
        int r = rem / 34;
        int c = rem - r * 34;
        int gh = tile_h0 + r - 1;
        int gw = tile_w0 + c - 1;
        float v = 0.f;
        if (gh >= 0 && gh < 128 && gw >= 0 && gw < 128)
            v = xg[(size_t)ci * 16384 + gh * 128 + gw];
        s_in[idx] = v;
    }
    __syncthreads();

    int lc = tid & 31;
    int lr0 = (tid >> 5) * 4;

#pragma unroll 1
    for (int i = 0; i < 4; ++i) {
        const float* wbase = rot + ((size_t)(i * 8 + b) * 8 + g) * 576;  // uniform -> s_load

        float acc[8][4];
#pragma unroll
        for (int co = 0; co < 8; ++co)
#pragma unroll
            for (int p = 0; p < 4; ++p) acc[co][p] = 0.f;

#pragma unroll
        for (int ci = 0; ci < 8; ++ci) {
            float v[6][3];
            int base = ci * 1156 + lr0 * 34 + lc;
#pragma unroll
            for (int r = 0; r < 6; ++r)
#pragma unroll
                for (int c = 0; c < 3; ++c)
                    v[r][c] = s_in[base + r * 34 + c];

#pragma unroll
            for (int co = 0; co < 8; ++co) {
                const float* wp = wbase + (co * 8 + ci) * 9;
#pragma unroll
                for (int ky = 0; ky < 3; ++ky)
#pragma unroll
                    for (int kx = 0; kx < 3; ++kx) {
                        float wv = wp[ky * 3 + kx];
#pragma unroll
                        for (int p = 0; p < 4; ++p)
                            acc[co][p] = fmaf(wv, v[p + ky][kx], acc[co][p]);
                    }
            }
        }

#pragma unroll
        for (int co = 0; co < 8; ++co) {
            int c = g * 8 + co;
            float mv = mod[i * 512 + b * 64 + c];
            __hip_bfloat16* op = bf + ((size_t)(i * 8 + b) * 64 + c) * 16384;
#pragma unroll
            for (int p = 0; p < 4; ++p) {
                int gh = tile_h0 + lr0 + p;
                op[gh * 128 + tile_w0 + lc] = __float2bfloat16(acc[co][p] * mv);
            }
        }
    }
}

// ---------------- Kernel 5 (v5): fused epilogue, SGPR weights, all-static indexing ----------------
// thread-per-pixel; grid 512 x 256.
__global__ void __launch_bounds__(256) k_mega(
    const float* __restrict__ x, const __hip_bfloat16* __restrict__ bfeat,
    const float* __restrict__ roi,
    const float* __restrict__ w1ts, const float* __restrict__ dsh,
    const float* __restrict__ w2, const float* __restrict__ b2,
    const float* __restrict__ ew1,
    const float* __restrict__ ebnw, const float* __restrict__ ebnb,
    const float* __restrict__ ebnm, const float* __restrict__ ebnv,
    const float* __restrict__ ew2, const float* __restrict__ eb2,
    float* __restrict__ out) {

    int tid = threadIdx.x;
    int p = blockIdx.x * 256 + tid;
    int b = p >> 14;
    int hw = p & 16383;
    int h = hw >> 7, w = hw & 127;

    const __hip_bfloat16* fb = bfeat + ((size_t)b * 64) * 16384 + hw;

    // ---- phase 1: y = (dir_w1*sc) @ feats_cat + dsh ----
    float y[64];
#pragma unroll
    for (int o = 0; o < 64; ++o) y[o] = dsh[o];
#pragma unroll 1
    for (int ch = 0; ch < 4; ++ch) {
        const __hip_bfloat16* fbi = fb + (size_t)ch * 512 * 16384;
        const float* wch = w1ts + ch * 4096;
#pragma unroll 1
        for (int j = 0; j < 64; ++j) {
            float fv = __bfloat162float(fbi[(size_t)j * 16384]);
            const float* wr = wch + j * 64;              // block-uniform -> SGPR
#pragma unroll
            for (int o = 0; o < 64; ++o) y[o] = fmaf(wr[o], fv, y[o]);
        }
    }
#pragma unroll
    for (int o = 0; o < 64; ++o) y[o] = fmaxf(y[o], 0.f);

    // ---- phase 2: logits + softmax ----
    float lg[4];
#pragma unroll
    for (int k = 0; k < 4; ++k) {
        float s = b2[k];
        const float* wr = w2 + k * 64;                   // uniform
#pragma unroll
        for (int o = 0; o < 64; ++o) s = fmaf(wr[o], y[o], s);
        lg[k] = s;
    }
    float mx = fmaxf(fmaxf(lg[0], lg[1]), fmaxf(lg[2], lg[3]));
    float e0 = expf(lg[0] - mx), e1s = expf(lg[1] - mx), e2s = expf(lg[2] - mx), e3s = expf(lg[3] - mx);
    float inv = 1.f / (e0 + e1s + e2s + e3s);
    float a0 = e0 * inv, a1 = e1s * inv, a2 = e2s * inv, a3 = e3s * inv;

    // ---- phase 3: roi bilinear (align_corners) ----
    float ysv = (float)h * (63.f / 127.f);
    float y0f = fminf(floorf(ysv), 62.f);
    float wy = ysv - y0f;
    float xsv = (float)w * (63.f / 127.f);
    float x0f = fminf(floorf(xsv), 62.f);
    float wx = xsv - x0f;
    int y0i = (int)y0f, x0i = (int)x0f;
    const float* rb = roi + (size_t)b * 4096;
    float r00 = rb[y0i * 64 + x0i], r01 = rb[y0i * 64 + x0i + 1];
    float r10 = rb[(y0i + 1) * 64 + x0i], r11 = rb[(y0i + 1) * 64 + x0i + 1];
    float rv = r00 * (1.f - wy) * (1.f - wx) + r01 * (1.f - wy) * wx
             + r10 * wy * (1.f - wx) + r11 * wy * wx;

    // ---- phase 4: fused = sum_i bf_i * attn_i, scaled by roi ----
    float f[64];
#pragma unroll
    for (int cc = 0; cc < 64; ++cc) {
        const __hip_bfloat16* pp = fb + (size_t)cc * 16384;
        float s = a0 * __bfloat162float(pp[0])
                + a1 * __bfloat162float(pp[(size_t)512 * 16384])
                + a2 * __bfloat162float(pp[(size_t)1024 * 16384])
                + a3 * __bfloat162float(pp[(size_t)1536 * 16384]);
        f[cc] = s * rv;
    }

    // ---- phase 5: edge MLP layer 1 (fully unrolled, inline BN) + relu ----
    float eh[32];
#pragma unroll
    for (int o = 0; o < 32; ++o) {
        float s = 0.f;
        const float* wr = ew1 + o * 64;                  // uniform
#pragma unroll
        for (int c = 0; c < 64; ++c) s = fmaf(wr[c], f[c], s);
        float sc = ebnw[o] * rsqrtf(ebnv[o] + 1e-5f);
        float sh = ebnb[o] - ebnm[o] * sc;
        eh[o] = fmaxf(fmaf(s, sc, sh), 0.f);
    }

    // ---- phase 6: e2 = sigmoid(ew2 @ eh + b), out = x*(1+e2) ----
    const float* xp = x + ((size_t)b * 64) * 16384 + hw;
    float* op = out + ((size_t)b * 64) * 16384 + hw;
#pragma unroll 1
    for (int cc = 0; cc < 64; ++cc) {
        float s = eb2[cc];
        const float* wr = ew2 + cc * 32;                 // uniform -> s_load
#pragma unroll
        for (int c = 0; c < 32; ++c) s = fmaf(wr[c], eh[c], s);
        float sg = 1.f / (1.f + expf(-s));
        float xv = xp[(size_t)cc * 16384];
        op[(size_t)cc * 16384] = xv + xv * sg;
    }
}

extern "C" void kernel_launch(void* const* d_in, const int* in_sizes, int n_in,
                              void* d_out, int out_size, void* d_ws, size_t ws_size,
                              hipStream_t stream) {
    const float* x    = (const float*)d_in[0];
    const float* roi  = (const float*)d_in[1];
    const float* bk   = (const float*)d_in[2];
    const float* aw1  = (const float*)d_in[3];
    const float* ab1  = (const float*)d_in[4];
    const float* aw2  = (const float*)d_in[5];
    const float* ab2  = (const float*)d_in[6];
    const float* mw1  = (const float*)d_in[7];
    const float* mb1  = (const float*)d_in[8];
    const float* mw2  = (const float*)d_in[9];
    const float* mb2  = (const float*)d_in[10];
    const float* w1   = (const float*)d_in[11];
    const float* bnw  = (const float*)d_in[12];
    const float* bnb  = (const float*)d_in[13];
    const float* bnm  = (const float*)d_in[14];
    const float* bnv  = (const float*)d_in[15];
    const float* w2   = (const float*)d_in[16];
    const float* b2   = (const float*)d_in[17];
    const float* ew1  = (const float*)d_in[18];
    const float* ebnw = (const float*)d_in[19];
    const float* ebnb = (const float*)d_in[20];
    const float* ebnm = (const float*)d_in[21];
    const float* ebnv = (const float*)d_in[22];
    const float* ew2  = (const float*)d_in[23];
    const float* eb2  = (const float*)d_in[24];

    float* ws     = (float*)d_ws;
    float* pooled = ws;                    // 512
    float* angles = ws + 512;              // 256
    float* mod    = ws + 768;              // 2048
    float* rot    = ws + 2816;             // 147456
    float* w1ts   = ws + 150272;           // 16384   (dedicated - no aliasing)
    float* dsh    = ws + 166656;           // 64
    __hip_bfloat16* bfeat = (__hip_bfloat16*)(ws + 166720);  // 33554432 bf16 = 64 MB

    k_prep<<<1, 256, 0, stream>>>(w1, bnw, bnb, bnm, bnv, w1ts, dsh);
    k_pool<<<512, 256, 0, stream>>>(x, pooled);
    k_mlp<<<32, 64, 0, stream>>>(pooled, aw1, ab1, aw2, ab2, mw1, mb1, mw2, mb2, angles, mod);
    k_rot<<<256, 64, 0, stream>>>(bk, angles, rot);
    k_conv<<<dim3(16, 64), 256, 0, stream>>>(x, rot, mod, bfeat);
    k_mega<<<512, 256, 0, stream>>>(x, bfeat, roi, w1ts, dsh, w2, b2,
                                    ew1, ebnw, ebnb, ebnm, ebnv, ew2, eb2,
                                    (float*)d_out);
}

// Round 7
// 294.106 us; speedup vs baseline: 1.8186x; 1.0222x over previous
//
#include <hip/hip_runtime.h>
#include <hip/hip_bf16.h>
#include <math.h>

#define PI4F 0.78539816339744830962f

// ---------------- Kernel 1: global average pool ----------------
__global__ void k_pool(const float* __restrict__ x, float* __restrict__ pooled) {
    int bc = blockIdx.x;
    const float* p = x + (size_t)bc * 16384;
    float s = 0.f;
    for (int j = threadIdx.x; j < 16384; j += 256) s += p[j];
    for (int off = 32; off > 0; off >>= 1) s += __shfl_xor(s, off, 64);
    __shared__ float red[4];
    int wave = threadIdx.x >> 6;
    if ((threadIdx.x & 63) == 0) red[wave] = s;
    __syncthreads();
    if (threadIdx.x == 0) {
        float t = red[0] + red[1] + red[2] + red[3];
        pooled[bc] = t * (1.0f / 16384.0f);
    }
}

// ---------------- Kernel 2: small MLPs -> angles, mod ----------------
__global__ void k_mlp(const float* __restrict__ pooled,
                      const float* __restrict__ aw1, const float* __restrict__ ab1,
                      const float* __restrict__ aw2, const float* __restrict__ ab2,
                      const float* __restrict__ mw1, const float* __restrict__ mb1,
                      const float* __restrict__ mw2, const float* __restrict__ mb2,
                      float* __restrict__ angles, float* __restrict__ mod) {
    int i = blockIdx.x >> 3, b = blockIdx.x & 7;
    int t = threadIdx.x;
    __shared__ float sp[64], sha[16], shm[16];
    sp[t] = pooled[b * 64 + t];
    __syncthreads();
    if (t < 16) {
        float sa = ab1[i * 16 + t], sm = mb1[i * 16 + t];
        const float* wa = aw1 + ((size_t)i * 16 + t) * 64;
        const float* wm = mw1 + ((size_t)i * 16 + t) * 64;
        for (int c = 0; c < 64; ++c) { sa = fmaf(wa[c], sp[c], sa); sm = fmaf(wm[c], sp[c], sm); }
        sha[t] = fmaxf(sa, 0.f);
        shm[t] = fmaxf(sm, 0.f);
    }
    __syncthreads();
    if (t < 8) {
        float s = ab2[i * 8 + t];
        const float* w = aw2 + ((size_t)i * 8 + t) * 16;
        for (int j = 0; j < 16; ++j) s = fmaf(w[j], sha[j], s);
        angles[i * 64 + b * 8 + t] = tanhf(s) * PI4F;
    }
    {
        float s = mb2[i * 64 + t];
        const float* w = mw2 + ((size_t)i * 64 + t) * 16;
        for (int j = 0; j < 16; ++j) s = fmaf(w[j], shm[j], s);
        mod[i * 512 + b * 64 + t] = 1.f / (1.f + expf(-s));
    }
}

// ---------------- Kernel 3: rotate base kernels ----------------
__global__ void k_rot(const float* __restrict__ bk, const float* __restrict__ angles,
                      float* __restrict__ rot) {
    int blk = blockIdx.x;
    int g = blk & 7, b = (blk >> 3) & 7, i = blk >> 6;
    float ang = angles[i * 64 + b * 8 + g];
    float st, ct;
    sincosf(ang, &st, &ct);
    int t = threadIdx.x;
    int co = t >> 3, ci = t & 7;
    const float* K = bk + ((((size_t)i * 8 + g) * 8 + co) * 8 + ci) * 9;
    float* R = rot + ((((size_t)i * 8 + b) * 8 + g) * 64 + t) * 9;
    for (int p = 0; p < 9; ++p) {
        int ky = p / 3, kx = p % 3;
        float xx = (float)kx - 1.f, yy = (float)ky - 1.f;
        float xr = xx * ct + yy * st + 1.f;
        float yr = -xx * st + yy * ct + 1.f;
        float x0 = fminf(fmaxf(floorf(xr), 0.f), 1.f);
        float y0 = fminf(fmaxf(floorf(yr), 0.f), 1.f);
        float x1 = x0 + 1.f, y1 = y0 + 1.f;
        float w00 = (x1 - xr) * (y1 - yr);
        float w01 = (x1 - xr) * (yr - y0);
        float w10 = (xr - x0) * (y1 - yr);
        float w11 = (xr - x0) * (yr - y0);
        int x0i = (int)x0, y0i = (int)y0;
        float v = w00 * K[y0i * 3 + x0i] + w01 * K[(y0i + 1) * 3 + x0i]
                + w10 * K[y0i * 3 + x0i + 1] + w11 * K[(y0i + 1) * 3 + x0i + 1];
        R[p] = v;
    }
}

// ---------------- Kernel 3.5: prep (w1 transpose + dir-BN scale fold) ----------------
__global__ void k_prep(const float* __restrict__ w1,
                       const float* __restrict__ bnw, const float* __restrict__ bnb,
                       const float* __restrict__ bnm, const float* __restrict__ bnv,
                       float* __restrict__ w1ts, float* __restrict__ dsh) {
    int tid = threadIdx.x;
    __shared__ float sc[64];
    if (tid < 64) {
        float s = bnw[tid] * rsqrtf(bnv[tid] + 1e-5f);
        sc[tid] = s;
        dsh[tid] = bnb[tid] - bnm[tid] * s;
    }
    __syncthreads();
    for (int q = tid; q < 16384; q += 256) {
        int o = q >> 8, k = q & 255;
        w1ts[k * 64 + o] = w1[q] * sc[o];    // scale folded into weights
    }
}

// ---------------- Kernel 4: tiled conv, 1 branch per pass, bf16 out ----------------
__global__ void __launch_bounds__(256) k_conv(const float* __restrict__ x,
                       const float* __restrict__ rot, const float* __restrict__ mod,
                       __hip_bfloat16* __restrict__ bf) {
    __shared__ float s_in[8 * 34 * 34];

    int bg = blockIdx.y;
    int b = bg >> 3, g = bg & 7;
    int tile_h0 = (blockIdx.x >> 2) * 32;
    int tile_w0 = (blockIdx.x & 3) * 32;
    int tid = threadIdx.x;

    const float* xg = x + ((size_t)b * 64 + (size_t)g * 8) * 16384;
    for (int idx = tid; idx < 8 * 1156; idx += 256) {
        int ci = idx / 1156;
        int rem = idx - ci * 1156;
        int r = rem / 34;
        int c = rem - r * 34;
        int gh = tile_h0 + r - 1;
        int gw = tile_w0 + c - 1;
        float v = 0.f;
        if (gh >= 0 && gh < 128 && gw >= 0 && gw < 128)
            v = xg[(size_t)ci * 16384 + gh * 128 + gw];
        s_in[idx] = v;
    }
    __syncthreads();

    int lc = tid & 31;
    int lr0 = (tid >> 5) * 4;

#pragma unroll 1
    for (int i = 0; i < 4; ++i) {
        const float* wbase = rot + ((size_t)(i * 8 + b) * 8 + g) * 576;  // uniform -> s_load

        float acc[8][4];
#pragma unroll
        for (int co = 0; co < 8; ++co)
#pragma unroll
            for (int p = 0; p < 4; ++p) acc[co][p] = 0.f;

#pragma unroll
        for (int ci = 0; ci < 8; ++ci) {
            float v[6][3];
            int base = ci * 1156 + lr0 * 34 + lc;
#pragma unroll
            for (int r = 0; r < 6; ++r)
#pragma unroll
                for (int c = 0; c < 3; ++c)
                    v[r][c] = s_in[base + r * 34 + c];

#pragma unroll
            for (int co = 0; co < 8; ++co) {
                const float* wp = wbase + (co * 8 + ci) * 9;
#pragma unroll
                for (int ky = 0; ky < 3; ++ky)
#pragma unroll
                    for (int kx = 0; kx < 3; ++kx) {
                        float wv = wp[ky * 3 + kx];
#pragma unroll
                        for (int p = 0; p < 4; ++p)
                            acc[co][p] = fmaf(wv, v[p + ky][kx], acc[co][p]);
                    }
            }
        }

#pragma unroll
        for (int co = 0; co < 8; ++co) {
            int c = g * 8 + co;
            float mv = mod[i * 512 + b * 64 + c];
            __hip_bfloat16* op = bf + ((size_t)(i * 8 + b) * 64 + c) * 16384;
#pragma unroll
            for (int p = 0; p < 4; ++p) {
                int gh = tile_h0 + lr0 + p;
                op[gh * 128 + tile_w0 + lc] = __float2bfloat16(acc[co][p] * mv);
            }
        }
    }
}

// ---------------- Kernel 5 (v6): fused epilogue, batched loads for ILP ----------------
// thread-per-pixel; grid 512 x 256. Latency-bound at 2 waves/SIMD (grid cap),
// so phase 1 batches 8 independent loads per group before the 512-FMA burst.
__global__ void __launch_bounds__(256) k_mega(
    const float* __restrict__ x, const __hip_bfloat16* __restrict__ bfeat,
    const float* __restrict__ roi,
    const float* __restrict__ w1ts, const float* __restrict__ dsh,
    const float* __restrict__ w2, const float* __restrict__ b2,
    const float* __restrict__ ew1,
    const float* __restrict__ ebnw, const float* __restrict__ ebnb,
    const float* __restrict__ ebnm, const float* __restrict__ ebnv,
    const float* __restrict__ ew2, const float* __restrict__ eb2,
    float* __restrict__ out) {

    int tid = threadIdx.x;
    int p = blockIdx.x * 256 + tid;
    int b = p >> 14;
    int hw = p & 16383;
    int h = hw >> 7, w = hw & 127;

    const __hip_bfloat16* fb = bfeat + ((size_t)b * 64) * 16384 + hw;

    // ---- phase 1: y = (dir_w1*sc) @ feats_cat + dsh ----
    float y[64];
#pragma unroll
    for (int o = 0; o < 64; ++o) y[o] = dsh[o];
#pragma unroll 1
    for (int ch = 0; ch < 4; ++ch) {
        const __hip_bfloat16* fbi = fb + (size_t)ch * 512 * 16384;
        const float* wch = w1ts + ch * 4096;
#pragma unroll 1
        for (int g = 0; g < 8; ++g) {
            // 8 independent loads in flight
            float f[8];
#pragma unroll
            for (int k = 0; k < 8; ++k)
                f[k] = __bfloat162float(fbi[(size_t)(g * 8 + k) * 16384]);
            const float* wg = wch + g * 512;             // block-uniform -> SGPR
#pragma unroll
            for (int k = 0; k < 8; ++k) {
#pragma unroll
                for (int o = 0; o < 64; ++o)
                    y[o] = fmaf(wg[k * 64 + o], f[k], y[o]);
            }
        }
    }
#pragma unroll
    for (int o = 0; o < 64; ++o) y[o] = fmaxf(y[o], 0.f);

    // ---- phase 2: logits + softmax ----
    float lg[4];
#pragma unroll
    for (int k = 0; k < 4; ++k) {
        float s = b2[k];
        const float* wr = w2 + k * 64;                   // uniform
#pragma unroll
        for (int o = 0; o < 64; ++o) s = fmaf(wr[o], y[o], s);
        lg[k] = s;
    }
    float mx = fmaxf(fmaxf(lg[0], lg[1]), fmaxf(lg[2], lg[3]));
    float e0 = expf(lg[0] - mx), e1s = expf(lg[1] - mx), e2s = expf(lg[2] - mx), e3s = expf(lg[3] - mx);
    float inv = 1.f / (e0 + e1s + e2s + e3s);
    float a0 = e0 * inv, a1 = e1s * inv, a2 = e2s * inv, a3 = e3s * inv;

    // ---- phase 3: roi bilinear (align_corners) ----
    float ysv = (float)h * (63.f / 127.f);
    float y0f = fminf(floorf(ysv), 62.f);
    float wy = ysv - y0f;
    float xsv = (float)w * (63.f / 127.f);
    float x0f = fminf(floorf(xsv), 62.f);
    float wx = xsv - x0f;
    int y0i = (int)y0f, x0i = (int)x0f;
    const float* rb = roi + (size_t)b * 4096;
    float r00 = rb[y0i * 64 + x0i], r01 = rb[y0i * 64 + x0i + 1];
    float r10 = rb[(y0i + 1) * 64 + x0i], r11 = rb[(y0i + 1) * 64 + x0i + 1];
    float rv = r00 * (1.f - wy) * (1.f - wx) + r01 * (1.f - wy) * wx
             + r10 * wy * (1.f - wx) + r11 * wy * wx;

    // ---- phase 4: fused = sum_i bf_i * attn_i, scaled by roi ----
    float f[64];
#pragma unroll
    for (int cc = 0; cc < 64; ++cc) {
        const __hip_bfloat16* pp = fb + (size_t)cc * 16384;
        float s = a0 * __bfloat162float(pp[0])
                + a1 * __bfloat162float(pp[(size_t)512 * 16384])
                + a2 * __bfloat162float(pp[(size_t)1024 * 16384])
                + a3 * __bfloat162float(pp[(size_t)1536 * 16384]);
        f[cc] = s * rv;
    }

    // ---- phase 5: edge MLP layer 1 (fully unrolled, inline BN) + relu ----
    float eh[32];
#pragma unroll
    for (int o = 0; o < 32; ++o) {
        float s = 0.f;
        const float* wr = ew1 + o * 64;                  // uniform
#pragma unroll
        for (int c = 0; c < 64; ++c) s = fmaf(wr[c], f[c], s);
        float sc = ebnw[o] * rsqrtf(ebnv[o] + 1e-5f);
        float sh = ebnb[o] - ebnm[o] * sc;
        eh[o] = fmaxf(fmaf(s, sc, sh), 0.f);
    }

    // ---- phase 6: e2 = sigmoid(ew2 @ eh + b), out = x*(1+e2) ----
    const float* xp = x + ((size_t)b * 64) * 16384 + hw;
    float* op = out + ((size_t)b * 64) * 16384 + hw;
#pragma unroll 4
    for (int cc = 0; cc < 64; ++cc) {
        float s = eb2[cc];
        const float* wr = ew2 + cc * 32;                 // uniform -> s_load
#pragma unroll
        for (int c = 0; c < 32; ++c) s = fmaf(wr[c], eh[c], s);
        float sg = 1.f / (1.f + expf(-s));
        float xv = xp[(size_t)cc * 16384];
        op[(size_t)cc * 16384] = xv + xv * sg;
    }
}

extern "C" void kernel_launch(void* const* d_in, const int* in_sizes, int n_in,
                              void* d_out, int out_size, void* d_ws, size_t ws_size,
                              hipStream_t stream) {
    const float* x    = (const float*)d_in[0];
    const float* roi  = (const float*)d_in[1];
    const float* bk   = (const float*)d_in[2];
    const float* aw1  = (const float*)d_in[3];
    const float* ab1  = (const float*)d_in[4];
    const float* aw2  = (const float*)d_in[5];
    const float* ab2  = (const float*)d_in[6];
    const float* mw1  = (const float*)d_in[7];
    const float* mb1  = (const float*)d_in[8];
    const float* mw2  = (const float*)d_in[9];
    const float* mb2  = (const float*)d_in[10];
    const float* w1   = (const float*)d_in[11];
    const float* bnw  = (const float*)d_in[12];
    const float* bnb  = (const float*)d_in[13];
    const float* bnm  = (const float*)d_in[14];
    const float* bnv  = (const float*)d_in[15];
    const float* w2   = (const float*)d_in[16];
    const float* b2   = (const float*)d_in[17];
    const float* ew1  = (const float*)d_in[18];
    const float* ebnw = (const float*)d_in[19];
    const float* ebnb = (const float*)d_in[20];
    const float* ebnm = (const float*)d_in[21];
    const float* ebnv = (const float*)d_in[22];
    const float* ew2  = (const float*)d_in[23];
    const float* eb2  = (const float*)d_in[24];

    float* ws     = (float*)d_ws;
    float* pooled = ws;                    // 512
    float* angles = ws + 512;              // 256
    float* mod    = ws + 768;              // 2048
    float* rot    = ws + 2816;             // 147456
    float* w1ts   = ws + 150272;           // 16384   (dedicated - no aliasing)
    float* dsh    = ws + 166656;           // 64
    __hip_bfloat16* bfeat = (__hip_bfloat16*)(ws + 166720);  // 64 MB

    k_prep<<<1, 256, 0, stream>>>(w1, bnw, bnb, bnm, bnv, w1ts, dsh);
    k_pool<<<512, 256, 0, stream>>>(x, pooled);
    k_mlp<<<32, 64, 0, stream>>>(pooled, aw1, ab1, aw2, ab2, mw1, mb1, mw2, mb2, angles, mod);
    k_rot<<<256, 64, 0, stream>>>(bk, angles, rot);
    k_conv<<<dim3(16, 64), 256, 0, stream>>>(x, rot, mod, bfeat);
    k_mega<<<512, 256, 0, stream>>>(x, bfeat, roi, w1ts, dsh, w2, b2,
                                    ew1, ebnw, ebnb, ebnm, ebnv, ew2, eb2,
                                    (float*)d_out);
}

// Round 8
// 273.449 us; speedup vs baseline: 1.9560x; 1.0755x over previous
//
#include <hip/hip_runtime.h>
#include <hip/hip_bf16.h>
#include <math.h>

#define PI4F 0.78539816339744830962f

typedef __attribute__((ext_vector_type(2))) __bf16 bf16x2_t;

__device__ __forceinline__ float dot2bf(unsigned int a, unsigned int b, float c) {
#if defined(__has_builtin) && __has_builtin(__builtin_amdgcn_fdot2_f32_bf16)
    return __builtin_amdgcn_fdot2_f32_bf16(__builtin_bit_cast(bf16x2_t, a),
                                           __builtin_bit_cast(bf16x2_t, b), c, false);
#else
    float a0 = __uint_as_float(a << 16), a1 = __uint_as_float(a & 0xffff0000u);
    float b0 = __uint_as_float(b << 16), b1 = __uint_as_float(b & 0xffff0000u);
    return fmaf(a1, b1, fmaf(a0, b0, c));
#endif
}

// ---------------- Kernel 1: global average pool (float4) ----------------
__global__ void k_pool(const float* __restrict__ x, float* __restrict__ pooled) {
    int bc = blockIdx.x;
    const float4* p4 = (const float4*)(x + (size_t)bc * 16384);
    float s = 0.f;
    for (int j = threadIdx.x; j < 4096; j += 256) {
        float4 v = p4[j];
        s += (v.x + v.y) + (v.z + v.w);
    }
    for (int off = 32; off > 0; off >>= 1) s += __shfl_xor(s, off, 64);
    __shared__ float red[4];
    int wave = threadIdx.x >> 6;
    if ((threadIdx.x & 63) == 0) red[wave] = s;
    __syncthreads();
    if (threadIdx.x == 0) {
        float t = red[0] + red[1] + red[2] + red[3];
        pooled[bc] = t * (1.0f / 16384.0f);
    }
}

// ---------------- Kernel 2: small MLPs -> angles, mod ----------------
__global__ void k_mlp(const float* __restrict__ pooled,
                      const float* __restrict__ aw1, const float* __restrict__ ab1,
                      const float* __restrict__ aw2, const float* __restrict__ ab2,
                      const float* __restrict__ mw1, const float* __restrict__ mb1,
                      const float* __restrict__ mw2, const float* __restrict__ mb2,
                      float* __restrict__ angles, float* __restrict__ mod) {
    int i = blockIdx.x >> 3, b = blockIdx.x & 7;
    int t = threadIdx.x;
    __shared__ float sp[64], sha[16], shm[16];
    sp[t] = pooled[b * 64 + t];
    __syncthreads();
    if (t < 16) {
        float sa = ab1[i * 16 + t], sm = mb1[i * 16 + t];
        const float* wa = aw1 + ((size_t)i * 16 + t) * 64;
        const float* wm = mw1 + ((size_t)i * 16 + t) * 64;
        for (int c = 0; c < 64; ++c) { sa = fmaf(wa[c], sp[c], sa); sm = fmaf(wm[c], sp[c], sm); }
        sha[t] = fmaxf(sa, 0.f);
        shm[t] = fmaxf(sm, 0.f);
    }
    __syncthreads();
    if (t < 8) {
        float s = ab2[i * 8 + t];
        const float* w = aw2 + ((size_t)i * 8 + t) * 16;
        for (int j = 0; j < 16; ++j) s = fmaf(w[j], sha[j], s);
        angles[i * 64 + b * 8 + t] = tanhf(s) * PI4F;
    }
    {
        float s = mb2[i * 64 + t];
        const float* w = mw2 + ((size_t)i * 64 + t) * 16;
        for (int j = 0; j < 16; ++j) s = fmaf(w[j], shm[j], s);
        mod[i * 512 + b * 64 + t] = 1.f / (1.f + expf(-s));
    }
}

// ---------------- Kernel 3: rotate base kernels ----------------
__global__ void k_rot(const float* __restrict__ bk, const float* __restrict__ angles,
                      float* __restrict__ rot) {
    int blk = blockIdx.x;
    int g = blk & 7, b = (blk >> 3) & 7, i = blk >> 6;
    float ang = angles[i * 64 + b * 8 + g];
    float st, ct;
    sincosf(ang, &st, &ct);
    int t = threadIdx.x;
    int co = t >> 3, ci = t & 7;
    const float* K = bk + ((((size_t)i * 8 + g) * 8 + co) * 8 + ci) * 9;
    float* R = rot + ((((size_t)i * 8 + b) * 8 + g) * 64 + t) * 9;
    for (int p = 0; p < 9; ++p) {
        int ky = p / 3, kx = p % 3;
        float xx = (float)kx - 1.f, yy = (float)ky - 1.f;
        float xr = xx * ct + yy * st + 1.f;
        float yr = -xx * st + yy * ct + 1.f;
        float x0 = fminf(fmaxf(floorf(xr), 0.f), 1.f);
        float y0 = fminf(fmaxf(floorf(yr), 0.f), 1.f);
        float x1 = x0 + 1.f, y1 = y0 + 1.f;
        float w00 = (x1 - xr) * (y1 - yr);
        float w01 = (x1 - xr) * (yr - y0);
        float w10 = (xr - x0) * (y1 - yr);
        float w11 = (xr - x0) * (yr - y0);
        int x0i = (int)x0, y0i = (int)y0;
        float v = w00 * K[y0i * 3 + x0i] + w01 * K[(y0i + 1) * 3 + x0i]
                + w10 * K[y0i * 3 + x0i + 1] + w11 * K[(y0i + 1) * 3 + x0i + 1];
        R[p] = v;
    }
}

// ---------------- Kernel 3.5: prep (w1 -> bf16 pairs with BN scale folded) ----------------
// w1p[pair][o], pair = ib*32+pp covers channels (ib*64+2pp, ib*64+2pp+1). Dedicated ws.
__global__ void k_prep(const float* __restrict__ w1,
                       const float* __restrict__ bnw, const float* __restrict__ bnb,
                       const float* __restrict__ bnm, const float* __restrict__ bnv,
                       unsigned int* __restrict__ w1p, float* __restrict__ dsh) {
    int tid = threadIdx.x;
    __shared__ float sc[64];
    if (tid < 64) {
        float s = bnw[tid] * rsqrtf(bnv[tid] + 1e-5f);
        sc[tid] = s;
        dsh[tid] = bnb[tid] - bnm[tid] * s;
    }
    __syncthreads();
    for (int q = tid; q < 8192; q += 256) {
        int pair = q >> 6;          // 0..127
        int o = q & 63;
        int ib = pair >> 5;
        int pp = pair & 31;
        int c0 = ib * 64 + 2 * pp;
        float v0 = w1[o * 256 + c0] * sc[o];
        float v1 = w1[o * 256 + c0 + 1] * sc[o];
        unsigned short b0 = __builtin_bit_cast(unsigned short, __float2bfloat16(v0));
        unsigned short b1 = __builtin_bit_cast(unsigned short, __float2bfloat16(v1));
        w1p[q] = (unsigned int)b0 | ((unsigned int)b1 << 16);
    }
}

// ---------------- Kernel 4 (v6): tiled conv, bf16 LDS tile (2x occupancy) ----------------
// grid (16, 64) = (tile, b*8+g); block 256. LDS 18.5 KB -> ~7 blocks/CU.
__global__ void __launch_bounds__(256) k_conv(const float* __restrict__ x,
                       const float* __restrict__ rot, const float* __restrict__ mod,
                       __hip_bfloat16* __restrict__ bf) {
    __shared__ unsigned short s_in[8 * 1156];   // 18496 B, bf16 bits

    int bg = blockIdx.y;
    int b = bg >> 3, g = bg & 7;
    int tile_h0 = (blockIdx.x >> 2) * 32;
    int tile_w0 = (blockIdx.x & 3) * 32;
    int tid = threadIdx.x;

    const float* xg = x + ((size_t)b * 64 + (size_t)g * 8) * 16384;
    for (int idx = tid; idx < 8 * 1156; idx += 256) {
        int ci = idx / 1156;
        int rem = idx - ci * 1156;
        int r = rem / 34;
        int c = rem - r * 34;
        int gh = tile_h0 + r - 1;
        int gw = tile_w0 + c - 1;
        float v = 0.f;
        if (gh >= 0 && gh < 128 && gw >= 0 && gw < 128)
            v = xg[(size_t)ci * 16384 + gh * 128 + gw];
        s_in[idx] = __builtin_bit_cast(unsigned short, __float2bfloat16(v));
    }
    __syncthreads();

    int lc = tid & 31;
    int lr0 = (tid >> 5) * 4;

#pragma unroll 1
    for (int i = 0; i < 4; ++i) {
        const float* wbase = rot + ((size_t)(i * 8 + b) * 8 + g) * 576;  // uniform -> s_load

        float acc[8][4];
#pragma unroll
        for (int co = 0; co < 8; ++co)
#pragma unroll
            for (int p = 0; p < 4; ++p) acc[co][p] = 0.f;

#pragma unroll
        for (int ci = 0; ci < 8; ++ci) {
            float v[6][3];
            int base = ci * 1156 + lr0 * 34 + lc;
#pragma unroll
            for (int r = 0; r < 6; ++r)
#pragma unroll
                for (int c = 0; c < 3; ++c)
                    v[r][c] = __uint_as_float(((unsigned int)s_in[base + r * 34 + c]) << 16);

#pragma unroll
            for (int co = 0; co < 8; ++co) {
                const float* wp = wbase + (co * 8 + ci) * 9;
#pragma unroll
                for (int ky = 0; ky < 3; ++ky)
#pragma unroll
                    for (int kx = 0; kx < 3; ++kx) {
                        float wv = wp[ky * 3 + kx];
#pragma unroll
                        for (int p = 0; p < 4; ++p)
                            acc[co][p] = fmaf(wv, v[p + ky][kx], acc[co][p]);
                    }
            }
        }

#pragma unroll
        for (int co = 0; co < 8; ++co) {
            int c = g * 8 + co;
            float mv = mod[i * 512 + b * 64 + c];
            __hip_bfloat16* op = bf + ((size_t)(i * 8 + b) * 64 + c) * 16384;
#pragma unroll
            for (int p = 0; p < 4; ++p) {
                int gh = tile_h0 + lr0 + p;
                op[gh * 128 + tile_w0 + lc] = __float2bfloat16(acc[co][p] * mv);
            }
        }
    }
}

// ---------------- Kernel 5 (v7): fused epilogue, dot2-bf16 phase 1 ----------------
// thread-per-pixel; grid 512 x 256.
__global__ void __launch_bounds__(256) k_mega(
    const float* __restrict__ x, const __hip_bfloat16* __restrict__ bfeat,
    const float* __restrict__ roi,
    const unsigned int* __restrict__ w1p, const float* __restrict__ dsh,
    const float* __restrict__ w2, const float* __restrict__ b2,
    const float* __restrict__ ew1,
    const float* __restrict__ ebnw, const float* __restrict__ ebnb,
    const float* __restrict__ ebnm, const float* __restrict__ ebnv,
    const float* __restrict__ ew2, const float* __restrict__ eb2,
    float* __restrict__ out) {

    int tid = threadIdx.x;
    int p = blockIdx.x * 256 + tid;
    int b = p >> 14;
    int hw = p & 16383;
    int h = hw >> 7, w = hw & 127;

    const __hip_bfloat16* fb = bfeat + ((size_t)b * 64) * 16384 + hw;
    const unsigned short* fbu = (const unsigned short*)fb;

    // ---- phase 1: y = (dir_w1*sc) @ feats_cat + dsh, via v_dot2_f32_bf16 ----
    float y[64];
#pragma unroll
    for (int o = 0; o < 64; ++o) y[o] = dsh[o];
#pragma unroll 1
    for (int ib = 0; ib < 4; ++ib) {
        const unsigned short* fbi = fbu + (size_t)ib * 512 * 16384;
        const unsigned int* wpB = w1p + ib * 2048;
#pragma unroll 1
        for (int g = 0; g < 8; ++g) {
            // 8 independent loads, packed into 4 bf16-pairs
            unsigned short us[8];
#pragma unroll
            for (int k = 0; k < 8; ++k)
                us[k] = fbi[(size_t)(g * 8 + k) * 16384];
            unsigned int pk[4];
#pragma unroll
            for (int q = 0; q < 4; ++q)
                pk[q] = (unsigned int)us[2 * q] | ((unsigned int)us[2 * q + 1] << 16);
            const unsigned int* wg = wpB + g * 256;      // block-uniform -> SGPR
#pragma unroll
            for (int q = 0; q < 4; ++q)
#pragma unroll
                for (int o = 0; o < 64; ++o)
                    y[o] = dot2bf(pk[q], wg[q * 64 + o], y[o]);
        }
    }
#pragma unroll
    for (int o = 0; o < 64; ++o) y[o] = fmaxf(y[o], 0.f);

    // ---- phase 2: logits + softmax ----
    float lg[4];
#pragma unroll
    for (int k = 0; k < 4; ++k) {
        float s = b2[k];
        const float* wr = w2 + k * 64;                   // uniform
#pragma unroll
        for (int o = 0; o < 64; ++o) s = fmaf(wr[o], y[o], s);
        lg[k] = s;
    }
    float mx = fmaxf(fmaxf(lg[0], lg[1]), fmaxf(lg[2], lg[3]));
    float e0 = expf(lg[0] - mx), e1s = expf(lg[1] - mx), e2s = expf(lg[2] - mx), e3s = expf(lg[3] - mx);
    float inv = 1.f / (e0 + e1s + e2s + e3s);
    float a0 = e0 * inv, a1 = e1s * inv, a2 = e2s * inv, a3 = e3s * inv;

    // ---- phase 3: roi bilinear (align_corners) ----
    float ysv = (float)h * (63.f / 127.f);
    float y0f = fminf(floorf(ysv), 62.f);
    float wy = ysv - y0f;
    float xsv = (float)w * (63.f / 127.f);
    float x0f = fminf(floorf(xsv), 62.f);
    float wx = xsv - x0f;
    int y0i = (int)y0f, x0i = (int)x0f;
    const float* rb = roi + (size_t)b * 4096;
    float r00 = rb[y0i * 64 + x0i], r01 = rb[y0i * 64 + x0i + 1];
    float r10 = rb[(y0i + 1) * 64 + x0i], r11 = rb[(y0i + 1) * 64 + x0i + 1];
    float rv = r00 * (1.f - wy) * (1.f - wx) + r01 * (1.f - wy) * wx
             + r10 * wy * (1.f - wx) + r11 * wy * wx;

    // ---- phase 4: fused = sum_i bf_i * attn_i, scaled by roi ----
    float f[64];
#pragma unroll
    for (int cc = 0; cc < 64; ++cc) {
        const __hip_bfloat16* pp = fb + (size_t)cc * 16384;
        float s = a0 * __bfloat162float(pp[0])
                + a1 * __bfloat162float(pp[(size_t)512 * 16384])
                + a2 * __bfloat162float(pp[(size_t)1024 * 16384])
                + a3 * __bfloat162float(pp[(size_t)1536 * 16384]);
        f[cc] = s * rv;
    }

    // ---- phase 5: edge MLP layer 1 (fully unrolled, inline BN) + relu ----
    float eh[32];
#pragma unroll
    for (int o = 0; o < 32; ++o) {
        float s = 0.f;
        const float* wr = ew1 + o * 64;                  // uniform
#pragma unroll
        for (int c = 0; c < 64; ++c) s = fmaf(wr[c], f[c], s);
        float sc = ebnw[o] * rsqrtf(ebnv[o] + 1e-5f);
        float sh = ebnb[o] - ebnm[o] * sc;
        eh[o] = fmaxf(fmaf(s, sc, sh), 0.f);
    }

    // ---- phase 6: e2 = sigmoid(ew2 @ eh + b), out = x*(1+e2) ----
    const float* xp = x + ((size_t)b * 64) * 16384 + hw;
    float* op = out + ((size_t)b * 64) * 16384 + hw;
#pragma unroll 4
    for (int cc = 0; cc < 64; ++cc) {
        float s = eb2[cc];
        const float* wr = ew2 + cc * 32;                 // uniform -> s_load
#pragma unroll
        for (int c = 0; c < 32; ++c) s = fmaf(wr[c], eh[c], s);
        float sg = 1.f / (1.f + expf(-s));
        float xv = xp[(size_t)cc * 16384];
        op[(size_t)cc * 16384] = xv + xv * sg;
    }
}

extern "C" void kernel_launch(void* const* d_in, const int* in_sizes, int n_in,
                              void* d_out, int out_size, void* d_ws, size_t ws_size,
                              hipStream_t stream) {
    const float* x    = (const float*)d_in[0];
    const float* roi  = (const float*)d_in[1];
    const float* bk   = (const float*)d_in[2];
    const float* aw1  = (const float*)d_in[3];
    const float* ab1  = (const float*)d_in[4];
    const float* aw2  = (const float*)d_in[5];
    const float* ab2  = (const float*)d_in[6];
    const float* mw1  = (const float*)d_in[7];
    const float* mb1  = (const float*)d_in[8];
    const float* mw2  = (const float*)d_in[9];
    const float* mb2  = (const float*)d_in[10];
    const float* w1   = (const float*)d_in[11];
    const float* bnw  = (const float*)d_in[12];
    const float* bnb  = (const float*)d_in[13];
    const float* bnm  = (const float*)d_in[14];
    const float* bnv  = (const float*)d_in[15];
    const float* w2   = (const float*)d_in[16];
    const float* b2   = (const float*)d_in[17];
    const float* ew1  = (const float*)d_in[18];
    const float* ebnw = (const float*)d_in[19];
    const float* ebnb = (const float*)d_in[20];
    const float* ebnm = (const float*)d_in[21];
    const float* ebnv = (const float*)d_in[22];
    const float* ew2  = (const float*)d_in[23];
    const float* eb2  = (const float*)d_in[24];

    float* ws     = (float*)d_ws;
    float* pooled = ws;                    // 512
    float* angles = ws + 512;              // 256
    float* mod    = ws + 768;              // 2048
    float* rot    = ws + 2816;             // 147456 -> ends 150272
    unsigned int* w1p = (unsigned int*)(ws + 150272);  // 8192 uints
    float* dsh    = ws + 158464;           // 64
    __hip_bfloat16* bfeat = (__hip_bfloat16*)(ws + 166720);  // 64 MB

    k_prep<<<1, 256, 0, stream>>>(w1, bnw, bnb, bnm, bnv, w1p, dsh);
    k_pool<<<512, 256, 0, stream>>>(x, pooled);
    k_mlp<<<32, 64, 0, stream>>>(pooled, aw1, ab1, aw2, ab2, mw1, mb1, mw2, mb2, angles, mod);
    k_rot<<<256, 64, 0, stream>>>(bk, angles, rot);
    k_conv<<<dim3(16, 64), 256, 0, stream>>>(x, rot, mod, bfeat);
    k_mega<<<512, 256, 0, stream>>>(x, bfeat, roi, w1p, dsh, w2, b2,
                                    ew1, ebnw, ebnb, ebnm, ebnv, ew2, eb2,
                                    (float*)d_out);
}

// Round 9
// 207.112 us; speedup vs baseline: 2.5825x; 1.3203x over previous
//
#include <hip/hip_runtime.h>
#include <hip/hip_bf16.h>
#include <math.h>

#define PI4F 0.78539816339744830962f

typedef __attribute__((ext_vector_type(2))) __bf16 bf16x2_t;

__device__ __forceinline__ float dot2bf(unsigned int a, unsigned int b, float c) {
#if defined(__has_builtin) && __has_builtin(__builtin_amdgcn_fdot2_f32_bf16)
    return __builtin_amdgcn_fdot2_f32_bf16(__builtin_bit_cast(bf16x2_t, a),
                                           __builtin_bit_cast(bf16x2_t, b), c, false);
#else
    float a0 = __uint_as_float(a << 16), a1 = __uint_as_float(a & 0xffff0000u);
    float b0 = __uint_as_float(b << 16), b1 = __uint_as_float(b & 0xffff0000u);
    return fmaf(a1, b1, fmaf(a0, b0, c));
#endif
}

__device__ __forceinline__ unsigned short bf16bits(float v) {
    return __builtin_bit_cast(unsigned short, __float2bfloat16(v));
}

// ---------------- Kernel 1: global average pool (float4) ----------------
__global__ void k_pool(const float* __restrict__ x, float* __restrict__ pooled) {
    int bc = blockIdx.x;
    const float4* p4 = (const float4*)(x + (size_t)bc * 16384);
    float s = 0.f;
    for (int j = threadIdx.x; j < 4096; j += 256) {
        float4 v = p4[j];
        s += (v.x + v.y) + (v.z + v.w);
    }
    for (int off = 32; off > 0; off >>= 1) s += __shfl_xor(s, off, 64);
    __shared__ float red[4];
    int wave = threadIdx.x >> 6;
    if ((threadIdx.x & 63) == 0) red[wave] = s;
    __syncthreads();
    if (threadIdx.x == 0) {
        float t = red[0] + red[1] + red[2] + red[3];
        pooled[bc] = t * (1.0f / 16384.0f);
    }
}

// ---------------- Kernel 2: small MLPs -> angles, mod ----------------
__global__ void k_mlp(const float* __restrict__ pooled,
                      const float* __restrict__ aw1, const float* __restrict__ ab1,
                      const float* __restrict__ aw2, const float* __restrict__ ab2,
                      const float* __restrict__ mw1, const float* __restrict__ mb1,
                      const float* __restrict__ mw2, const float* __restrict__ mb2,
                      float* __restrict__ angles, float* __restrict__ mod) {
    int i = blockIdx.x >> 3, b = blockIdx.x & 7;
    int t = threadIdx.x;
    __shared__ float sp[64], sha[16], shm[16];
    sp[t] = pooled[b * 64 + t];
    __syncthreads();
    if (t < 16) {
        float sa = ab1[i * 16 + t], sm = mb1[i * 16 + t];
        const float* wa = aw1 + ((size_t)i * 16 + t) * 64;
        const float* wm = mw1 + ((size_t)i * 16 + t) * 64;
        for (int c = 0; c < 64; ++c) { sa = fmaf(wa[c], sp[c], sa); sm = fmaf(wm[c], sp[c], sm); }
        sha[t] = fmaxf(sa, 0.f);
        shm[t] = fmaxf(sm, 0.f);
    }
    __syncthreads();
    if (t < 8) {
        float s = ab2[i * 8 + t];
        const float* w = aw2 + ((size_t)i * 8 + t) * 16;
        for (int j = 0; j < 16; ++j) s = fmaf(w[j], sha[j], s);
        angles[i * 64 + b * 8 + t] = tanhf(s) * PI4F;
    }
    {
        float s = mb2[i * 64 + t];
        const float* w = mw2 + ((size_t)i * 64 + t) * 16;
        for (int j = 0; j < 16; ++j) s = fmaf(w[j], shm[j], s);
        mod[i * 512 + b * 64 + t] = 1.f / (1.f + expf(-s));
    }
}

// ---------------- Kernel 3 (v2): rotate base kernels -> bf16 pair-packed ----------------
// grid 256 = ((i*8+b)*8+g), block 64 (co,ci).
// rotp layout per block: [co][pos][q] u32 (q = ci pair), 288 u32.
__global__ void k_rot(const float* __restrict__ bk, const float* __restrict__ angles,
                      unsigned int* __restrict__ rotp) {
    int blk = blockIdx.x;
    int g = blk & 7, b = (blk >> 3) & 7, i = blk >> 6;
    float ang = angles[i * 64 + b * 8 + g];
    float st, ct;
    sincosf(ang, &st, &ct);
    int t = threadIdx.x;
    int co = t >> 3, ci = t & 7;
    const float* K = bk + ((((size_t)i * 8 + g) * 8 + co) * 8 + ci) * 9;
    __shared__ float tmp[576];   // [co*8+ci][pos]
#pragma unroll
    for (int p = 0; p < 9; ++p) {
        int ky = p / 3, kx = p % 3;
        float xx = (float)kx - 1.f, yy = (float)ky - 1.f;
        float xr = xx * ct + yy * st + 1.f;
        float yr = -xx * st + yy * ct + 1.f;
        float x0 = fminf(fmaxf(floorf(xr), 0.f), 1.f);
        float y0 = fminf(fmaxf(floorf(yr), 0.f), 1.f);
        float x1 = x0 + 1.f, y1 = y0 + 1.f;
        float w00 = (x1 - xr) * (y1 - yr);
        float w01 = (x1 - xr) * (yr - y0);
        float w10 = (xr - x0) * (y1 - yr);
        float w11 = (xr - x0) * (yr - y0);
        int x0i = (int)x0, y0i = (int)y0;
        float v = w00 * K[y0i * 3 + x0i] + w01 * K[(y0i + 1) * 3 + x0i]
                + w10 * K[y0i * 3 + x0i + 1] + w11 * K[(y0i + 1) * 3 + x0i + 1];
        tmp[t * 9 + p] = v;
    }
    __syncthreads();
    unsigned int* R = rotp + (size_t)blk * 288;
    for (int ot = t; ot < 288; ot += 64) {
        int co2 = ot / 36;
        int rem = ot - co2 * 36;
        int pos = rem >> 2;
        int q = rem & 3;
        float v0 = tmp[(co2 * 8 + 2 * q) * 9 + pos];
        float v1 = tmp[(co2 * 8 + 2 * q + 1) * 9 + pos];
        R[ot] = (unsigned int)bf16bits(v0) | ((unsigned int)bf16bits(v1) << 16);
    }
}

// ---------------- Kernel 3.5: prep (w1 -> bf16 pairs with BN scale folded) ----------------
__global__ void k_prep(const float* __restrict__ w1,
                       const float* __restrict__ bnw, const float* __restrict__ bnb,
                       const float* __restrict__ bnm, const float* __restrict__ bnv,
                       unsigned int* __restrict__ w1p, float* __restrict__ dsh) {
    int tid = threadIdx.x;
    __shared__ float sc[64];
    if (tid < 64) {
        float s = bnw[tid] * rsqrtf(bnv[tid] + 1e-5f);
        sc[tid] = s;
        dsh[tid] = bnb[tid] - bnm[tid] * s;
    }
    __syncthreads();
    for (int q = tid; q < 8192; q += 256) {
        int pair = q >> 6;          // 0..127
        int o = q & 63;
        int ib = pair >> 5;
        int pp = pair & 31;
        int c0 = ib * 64 + 2 * pp;
        float v0 = w1[o * 256 + c0] * sc[o];
        float v1 = w1[o * 256 + c0 + 1] * sc[o];
        w1p[q] = (unsigned int)bf16bits(v0) | ((unsigned int)bf16bits(v1) << 16);
    }
}

// ---------------- Kernel 4 (v7): tiled conv, dot2-bf16, read-once registers ----------------
// grid (16, 64) = (tile, b*8+g); block 256.
// LDS: [pixel][ci] bf16, 20B row stride (stride-5 dwords -> conflict-free).
__global__ void __launch_bounds__(256) k_conv(const float* __restrict__ x,
                       const unsigned int* __restrict__ rotp, const float* __restrict__ mod,
                       __hip_bfloat16* __restrict__ bf) {
    __shared__ unsigned int s_in[1156 * 5];     // 23120 B
    unsigned short* s16 = (unsigned short*)s_in;

    int bg = blockIdx.y;
    int b = bg >> 3, g = bg & 7;
    int tile_h0 = (blockIdx.x >> 2) * 32;
    int tile_w0 = (blockIdx.x & 3) * 32;
    int tid = threadIdx.x;

    // ---- stage: plane-major coalesced reads, packed u16 LDS writes ----
    const float* xg = x + ((size_t)b * 64 + (size_t)g * 8) * 16384;
    for (int idx = tid; idx < 8 * 1156; idx += 256) {
        int ci = idx / 1156;
        int pix = idx - ci * 1156;
        int r = pix / 34;
        int c = pix - r * 34;
        int gh = tile_h0 + r - 1;
        int gw = tile_w0 + c - 1;
        float v = 0.f;
        if (gh >= 0 && gh < 128 && gw >= 0 && gw < 128)
            v = xg[(size_t)ci * 16384 + gh * 128 + gw];
        s16[pix * 10 + ci] = bf16bits(v);
    }
    __syncthreads();

    int lc = tid & 31;
    int lr0 = (tid >> 5) * 4;

    // ---- read 6x3 neighborhood ONCE (all 8 ci packed in 4 dwords/pixel) ----
    unsigned int vv[6][3][4];
#pragma unroll
    for (int r = 0; r < 6; ++r)
#pragma unroll
        for (int c = 0; c < 3; ++c) {
            int pix = (lr0 + r) * 34 + lc + c;
#pragma unroll
            for (int q = 0; q < 4; ++q)
                vv[r][c][q] = s_in[pix * 5 + q];
        }

#pragma unroll 1
    for (int i = 0; i < 4; ++i) {
        const unsigned int* wb = rotp + ((size_t)(i * 8 + b) * 8 + g) * 288;  // uniform -> s_load

        float acc[8][4];
#pragma unroll
        for (int co = 0; co < 8; ++co)
#pragma unroll
            for (int p = 0; p < 4; ++p) acc[co][p] = 0.f;

#pragma unroll
        for (int co = 0; co < 8; ++co) {
#pragma unroll
            for (int ky = 0; ky < 3; ++ky)
#pragma unroll
                for (int kx = 0; kx < 3; ++kx) {
#pragma unroll
                    for (int q = 0; q < 4; ++q) {
                        unsigned int wv = wb[co * 36 + (ky * 3 + kx) * 4 + q];  // SGPR
#pragma unroll
                        for (int p = 0; p < 4; ++p)
                            acc[co][p] = dot2bf(vv[p + ky][kx][q], wv, acc[co][p]);
                    }
                }
        }

#pragma unroll
        for (int co = 0; co < 8; ++co) {
            int c = g * 8 + co;
            float mv = mod[i * 512 + b * 64 + c];
            __hip_bfloat16* op = bf + ((size_t)(i * 8 + b) * 64 + c) * 16384;
#pragma unroll
            for (int p = 0; p < 4; ++p) {
                int gh = tile_h0 + lr0 + p;
                op[gh * 128 + tile_w0 + lc] = __float2bfloat16(acc[co][p] * mv);
            }
        }
    }
}

// ---------------- Kernel 5 (v7): fused epilogue, dot2-bf16 phase 1 ----------------
__global__ void __launch_bounds__(256) k_mega(
    const float* __restrict__ x, const __hip_bfloat16* __restrict__ bfeat,
    const float* __restrict__ roi,
    const unsigned int* __restrict__ w1p, const float* __restrict__ dsh,
    const float* __restrict__ w2, const float* __restrict__ b2,
    const float* __restrict__ ew1,
    const float* __restrict__ ebnw, const float* __restrict__ ebnb,
    const float* __restrict__ ebnm, const float* __restrict__ ebnv,
    const float* __restrict__ ew2, const float* __restrict__ eb2,
    float* __restrict__ out) {

    int tid = threadIdx.x;
    int p = blockIdx.x * 256 + tid;
    int b = p >> 14;
    int hw = p & 16383;
    int h = hw >> 7, w = hw & 127;

    const __hip_bfloat16* fb = bfeat + ((size_t)b * 64) * 16384 + hw;
    const unsigned short* fbu = (const unsigned short*)fb;

    // ---- phase 1: y = (dir_w1*sc) @ feats_cat + dsh, via v_dot2_f32_bf16 ----
    float y[64];
#pragma unroll
    for (int o = 0; o < 64; ++o) y[o] = dsh[o];
#pragma unroll 1
    for (int ib = 0; ib < 4; ++ib) {
        const unsigned short* fbi = fbu + (size_t)ib * 512 * 16384;
        const unsigned int* wpB = w1p + ib * 2048;
#pragma unroll 1
        for (int g = 0; g < 8; ++g) {
            unsigned short us[8];
#pragma unroll
            for (int k = 0; k < 8; ++k)
                us[k] = fbi[(size_t)(g * 8 + k) * 16384];
            unsigned int pk[4];
#pragma unroll
            for (int q = 0; q < 4; ++q)
                pk[q] = (unsigned int)us[2 * q] | ((unsigned int)us[2 * q + 1] << 16);
            const unsigned int* wg = wpB + g * 256;      // block-uniform -> SGPR
#pragma unroll
            for (int q = 0; q < 4; ++q)
#pragma unroll
                for (int o = 0; o < 64; ++o)
                    y[o] = dot2bf(pk[q], wg[q * 64 + o], y[o]);
        }
    }
#pragma unroll
    for (int o = 0; o < 64; ++o) y[o] = fmaxf(y[o], 0.f);

    // ---- phase 2: logits + softmax ----
    float lg[4];
#pragma unroll
    for (int k = 0; k < 4; ++k) {
        float s = b2[k];
        const float* wr = w2 + k * 64;                   // uniform
#pragma unroll
        for (int o = 0; o < 64; ++o) s = fmaf(wr[o], y[o], s);
        lg[k] = s;
    }
    float mx = fmaxf(fmaxf(lg[0], lg[1]), fmaxf(lg[2], lg[3]));
    float e0 = expf(lg[0] - mx), e1s = expf(lg[1] - mx), e2s = expf(lg[2] - mx), e3s = expf(lg[3] - mx);
    float inv = 1.f / (e0 + e1s + e2s + e3s);
    float a0 = e0 * inv, a1 = e1s * inv, a2 = e2s * inv, a3 = e3s * inv;

    // ---- phase 3: roi bilinear (align_corners) ----
    float ysv = (float)h * (63.f / 127.f);
    float y0f = fminf(floorf(ysv), 62.f);
    float wy = ysv - y0f;
    float xsv = (float)w * (63.f / 127.f);
    float x0f = fminf(floorf(xsv), 62.f);
    float wx = xsv - x0f;
    int y0i = (int)y0f, x0i = (int)x0f;
    const float* rb = roi + (size_t)b * 4096;
    float r00 = rb[y0i * 64 + x0i], r01 = rb[y0i * 64 + x0i + 1];
    float r10 = rb[(y0i + 1) * 64 + x0i], r11 = rb[(y0i + 1) * 64 + x0i + 1];
    float rv = r00 * (1.f - wy) * (1.f - wx) + r01 * (1.f - wy) * wx
             + r10 * wy * (1.f - wx) + r11 * wy * wx;

    // ---- phase 4: fused = sum_i bf_i * attn_i, scaled by roi ----
    float f[64];
#pragma unroll
    for (int cc = 0; cc < 64; ++cc) {
        const __hip_bfloat16* pp = fb + (size_t)cc * 16384;
        float s = a0 * __bfloat162float(pp[0])
                + a1 * __bfloat162float(pp[(size_t)512 * 16384])
                + a2 * __bfloat162float(pp[(size_t)1024 * 16384])
                + a3 * __bfloat162float(pp[(size_t)1536 * 16384]);
        f[cc] = s * rv;
    }

    // ---- phase 5: edge MLP layer 1 (fully unrolled, inline BN) + relu ----
    float eh[32];
#pragma unroll
    for (int o = 0; o < 32; ++o) {
        float s = 0.f;
        const float* wr = ew1 + o * 64;                  // uniform
#pragma unroll
        for (int c = 0; c < 64; ++c) s = fmaf(wr[c], f[c], s);
        float sc = ebnw[o] * rsqrtf(ebnv[o] + 1e-5f);
        float sh = ebnb[o] - ebnm[o] * sc;
        eh[o] = fmaxf(fmaf(s, sc, sh), 0.f);
    }

    // ---- phase 6: e2 = sigmoid(ew2 @ eh + b), out = x*(1+e2) ----
    const float* xp = x + ((size_t)b * 64) * 16384 + hw;
    float* op = out + ((size_t)b * 64) * 16384 + hw;
#pragma unroll 4
    for (int cc = 0; cc < 64; ++cc) {
        float s = eb2[cc];
        const float* wr = ew2 + cc * 32;                 // uniform -> s_load
#pragma unroll
        for (int c = 0; c < 32; ++c) s = fmaf(wr[c], eh[c], s);
        float sg = 1.f / (1.f + expf(-s));
        float xv = xp[(size_t)cc * 16384];
        op[(size_t)cc * 16384] = xv + xv * sg;
    }
}

extern "C" void kernel_launch(void* const* d_in, const int* in_sizes, int n_in,
                              void* d_out, int out_size, void* d_ws, size_t ws_size,
                              hipStream_t stream) {
    const float* x    = (const float*)d_in[0];
    const float* roi  = (const float*)d_in[1];
    const float* bk   = (const float*)d_in[2];
    const float* aw1  = (const float*)d_in[3];
    const float* ab1  = (const float*)d_in[4];
    const float* aw2  = (const float*)d_in[5];
    const float* ab2  = (const float*)d_in[6];
    const float* mw1  = (const float*)d_in[7];
    const float* mb1  = (const float*)d_in[8];
    const float* mw2  = (const float*)d_in[9];
    const float* mb2  = (const float*)d_in[10];
    const float* w1   = (const float*)d_in[11];
    const float* bnw  = (const float*)d_in[12];
    const float* bnb  = (const float*)d_in[13];
    const float* bnm  = (const float*)d_in[14];
    const float* bnv  = (const float*)d_in[15];
    const float* w2   = (const float*)d_in[16];
    const float* b2   = (const float*)d_in[17];
    const float* ew1  = (const float*)d_in[18];
    const float* ebnw = (const float*)d_in[19];
    const float* ebnb = (const float*)d_in[20];
    const float* ebnm = (const float*)d_in[21];
    const float* ebnv = (const float*)d_in[22];
    const float* ew2  = (const float*)d_in[23];
    const float* eb2  = (const float*)d_in[24];

    float* ws     = (float*)d_ws;
    float* pooled = ws;                    // 512
    float* angles = ws + 512;              // 256
    float* mod    = ws + 768;              // 2048
    unsigned int* rotp = (unsigned int*)(ws + 2816);   // 73728 uints -> ends 76544
    unsigned int* w1p  = (unsigned int*)(ws + 150272); // 8192 uints
    float* dsh    = ws + 158464;           // 64
    __hip_bfloat16* bfeat = (__hip_bfloat16*)(ws + 166720);  // 64 MB

    k_prep<<<1, 256, 0, stream>>>(w1, bnw, bnb, bnm, bnv, w1p, dsh);
    k_pool<<<512, 256, 0, stream>>>(x, pooled);
    k_mlp<<<32, 64, 0, stream>>>(pooled, aw1, ab1, aw2, ab2, mw1, mb1, mw2, mb2, angles, mod);
    k_rot<<<256, 64, 0, stream>>>(bk, angles, rotp);
    k_conv<<<dim3(16, 64), 256, 0, stream>>>(x, rotp, mod, bfeat);
    k_mega<<<512, 256, 0, stream>>>(x, bfeat, roi, w1p, dsh, w2, b2,
                                    ew1, ebnw, ebnb, ebnm, ebnv, ew2, eb2,
                                    (float*)d_out);
}

// Round 10
// 166.396 us; speedup vs baseline: 3.2144x; 1.2447x over previous
//
#include <hip/hip_runtime.h>
#include <hip/hip_bf16.h>
#include <math.h>

#define PI4F 0.78539816339744830962f

typedef __attribute__((ext_vector_type(2))) __bf16 bf16x2_t;
typedef __attribute__((ext_vector_type(8))) short s8v;      // bf16x8 MFMA operand
typedef __attribute__((ext_vector_type(4))) float f32x4;    // MFMA accumulator
typedef __attribute__((ext_vector_type(4))) unsigned int uint4v;

__device__ __forceinline__ float dot2bf(unsigned int a, unsigned int b, float c) {
#if defined(__has_builtin) && __has_builtin(__builtin_amdgcn_fdot2_f32_bf16)
    return __builtin_amdgcn_fdot2_f32_bf16(__builtin_bit_cast(bf16x2_t, a),
                                           __builtin_bit_cast(bf16x2_t, b), c, false);
#else
    float a0 = __uint_as_float(a << 16), a1 = __uint_as_float(a & 0xffff0000u);
    float b0 = __uint_as_float(b << 16), b1 = __uint_as_float(b & 0xffff0000u);
    return fmaf(a1, b1, fmaf(a0, b0, c));
#endif
}

__device__ __forceinline__ unsigned short bf16bits(float v) {
    return __builtin_bit_cast(unsigned short, __float2bfloat16(v));
}

// ---------------- Kernel 1: global average pool (float4) ----------------
__global__ void k_pool(const float* __restrict__ x, float* __restrict__ pooled) {
    int bc = blockIdx.x;
    const float4* p4 = (const float4*)(x + (size_t)bc * 16384);
    float s = 0.f;
    for (int j = threadIdx.x; j < 4096; j += 256) {
        float4 v = p4[j];
        s += (v.x + v.y) + (v.z + v.w);
    }
    for (int off = 32; off > 0; off >>= 1) s += __shfl_xor(s, off, 64);
    __shared__ float red[4];
    int wave = threadIdx.x >> 6;
    if ((threadIdx.x & 63) == 0) red[wave] = s;
    __syncthreads();
    if (threadIdx.x == 0) {
        float t = red[0] + red[1] + red[2] + red[3];
        pooled[bc] = t * (1.0f / 16384.0f);
    }
}

// ---------------- Kernel 2: small MLPs -> angles, mod ----------------
__global__ void k_mlp(const float* __restrict__ pooled,
                      const float* __restrict__ aw1, const float* __restrict__ ab1,
                      const float* __restrict__ aw2, const float* __restrict__ ab2,
                      const float* __restrict__ mw1, const float* __restrict__ mb1,
                      const float* __restrict__ mw2, const float* __restrict__ mb2,
                      float* __restrict__ angles, float* __restrict__ mod) {
    int i = blockIdx.x >> 3, b = blockIdx.x & 7;
    int t = threadIdx.x;
    __shared__ float sp[64], sha[16], shm[16];
    sp[t] = pooled[b * 64 + t];
    __syncthreads();
    if (t < 16) {
        float sa = ab1[i * 16 + t], sm = mb1[i * 16 + t];
        const float* wa = aw1 + ((size_t)i * 16 + t) * 64;
        const float* wm = mw1 + ((size_t)i * 16 + t) * 64;
        for (int c = 0; c < 64; ++c) { sa = fmaf(wa[c], sp[c], sa); sm = fmaf(wm[c], sp[c], sm); }
        sha[t] = fmaxf(sa, 0.f);
        shm[t] = fmaxf(sm, 0.f);
    }
    __syncthreads();
    if (t < 8) {
        float s = ab2[i * 8 + t];
        const float* w = aw2 + ((size_t)i * 8 + t) * 16;
        for (int j = 0; j < 16; ++j) s = fmaf(w[j], sha[j], s);
        angles[i * 64 + b * 8 + t] = tanhf(s) * PI4F;
    }
    {
        float s = mb2[i * 64 + t];
        const float* w = mw2 + ((size_t)i * 64 + t) * 16;
        for (int j = 0; j < 16; ++j) s = fmaf(w[j], shm[j], s);
        mod[i * 512 + b * 64 + t] = 1.f / (1.f + expf(-s));
    }
}

// ---------------- Kernel 3 (v2): rotate base kernels -> bf16 pair-packed ----------------
__global__ void k_rot(const float* __restrict__ bk, const float* __restrict__ angles,
                      unsigned int* __restrict__ rotp) {
    int blk = blockIdx.x;
    int g = blk & 7, b = (blk >> 3) & 7, i = blk >> 6;
    float ang = angles[i * 64 + b * 8 + g];
    float st, ct;
    sincosf(ang, &st, &ct);
    int t = threadIdx.x;
    int co = t >> 3, ci = t & 7;
    const float* K = bk + ((((size_t)i * 8 + g) * 8 + co) * 8 + ci) * 9;
    __shared__ float tmp[576];
#pragma unroll
    for (int p = 0; p < 9; ++p) {
        int ky = p / 3, kx = p % 3;
        float xx = (float)kx - 1.f, yy = (float)ky - 1.f;
        float xr = xx * ct + yy * st + 1.f;
        float yr = -xx * st + yy * ct + 1.f;
        float x0 = fminf(fmaxf(floorf(xr), 0.f), 1.f);
        float y0 = fminf(fmaxf(floorf(yr), 0.f), 1.f);
        float x1 = x0 + 1.f, y1 = y0 + 1.f;
        float w00 = (x1 - xr) * (y1 - yr);
        float w01 = (x1 - xr) * (yr - y0);
        float w10 = (xr - x0) * (y1 - yr);
        float w11 = (xr - x0) * (yr - y0);
        int x0i = (int)x0, y0i = (int)y0;
        float v = w00 * K[y0i * 3 + x0i] + w01 * K[(y0i + 1) * 3 + x0i]
                + w10 * K[y0i * 3 + x0i + 1] + w11 * K[(y0i + 1) * 3 + x0i + 1];
        tmp[t * 9 + p] = v;
    }
    __syncthreads();
    unsigned int* R = rotp + (size_t)blk * 288;
    for (int ot = t; ot < 288; ot += 64) {
        int co2 = ot / 36;
        int rem = ot - co2 * 36;
        int pos = rem >> 2;
        int q = rem & 3;
        float v0 = tmp[(co2 * 8 + 2 * q) * 9 + pos];
        float v1 = tmp[(co2 * 8 + 2 * q + 1) * 9 + pos];
        R[ot] = (unsigned int)bf16bits(v0) | ((unsigned int)bf16bits(v1) << 16);
    }
}

// ---------------- Kernel 3.5: prep (w1*scale -> MFMA B-fragment order, bf16) ----------------
// w1f[q]: q = nt*2048 + ks*256 + l*4 + jp ; covers B[k][n] with
// n = nt*16 + (l&15), k = ks*32 + (l>>4)*8 + jp*2 (+1 in high half).
__global__ void k_prep(const float* __restrict__ w1,
                       const float* __restrict__ bnw, const float* __restrict__ bnb,
                       const float* __restrict__ bnm, const float* __restrict__ bnv,
                       unsigned int* __restrict__ w1f, float* __restrict__ dsh) {
    int tid = threadIdx.x;
    __shared__ float sc[64];
    if (tid < 64) {
        float s = bnw[tid] * rsqrtf(bnv[tid] + 1e-5f);
        sc[tid] = s;
        dsh[tid] = bnb[tid] - bnm[tid] * s;
    }
    __syncthreads();
    for (int q = tid; q < 8192; q += 256) {
        int jp = q & 3;
        int l  = (q >> 2) & 63;
        int ks = (q >> 8) & 7;
        int nt = q >> 11;
        int o = nt * 16 + (l & 15);
        int k = ks * 32 + (l >> 4) * 8 + jp * 2;
        float v0 = w1[o * 256 + k] * sc[o];
        float v1 = w1[o * 256 + k + 1] * sc[o];
        w1f[q] = (unsigned int)bf16bits(v0) | ((unsigned int)bf16bits(v1) << 16);
    }
}

// ---------------- Kernel 4 (v7): tiled conv, dot2-bf16, read-once registers ----------------
__global__ void __launch_bounds__(256) k_conv(const float* __restrict__ x,
                       const unsigned int* __restrict__ rotp, const float* __restrict__ mod,
                       __hip_bfloat16* __restrict__ bf) {
    __shared__ unsigned int s_in[1156 * 5];
    unsigned short* s16 = (unsigned short*)s_in;

    int bg = blockIdx.y;
    int b = bg >> 3, g = bg & 7;
    int tile_h0 = (blockIdx.x >> 2) * 32;
    int tile_w0 = (blockIdx.x & 3) * 32;
    int tid = threadIdx.x;

    const float* xg = x + ((size_t)b * 64 + (size_t)g * 8) * 16384;
    for (int idx = tid; idx < 8 * 1156; idx += 256) {
        int ci = idx / 1156;
        int pix = idx - ci * 1156;
        int r = pix / 34;
        int c = pix - r * 34;
        int gh = tile_h0 + r - 1;
        int gw = tile_w0 + c - 1;
        float v = 0.f;
        if (gh >= 0 && gh < 128 && gw >= 0 && gw < 128)
            v = xg[(size_t)ci * 16384 + gh * 128 + gw];
        s16[pix * 10 + ci] = bf16bits(v);
    }
    __syncthreads();

    int lc = tid & 31;
    int lr0 = (tid >> 5) * 4;

    unsigned int vv[6][3][4];
#pragma unroll
    for (int r = 0; r < 6; ++r)
#pragma unroll
        for (int c = 0; c < 3; ++c) {
            int pix = (lr0 + r) * 34 + lc + c;
#pragma unroll
            for (int q = 0; q < 4; ++q)
                vv[r][c][q] = s_in[pix * 5 + q];
        }

#pragma unroll 1
    for (int i = 0; i < 4; ++i) {
        const unsigned int* wb = rotp + ((size_t)(i * 8 + b) * 8 + g) * 288;

        float acc[8][4];
#pragma unroll
        for (int co = 0; co < 8; ++co)
#pragma unroll
            for (int p = 0; p < 4; ++p) acc[co][p] = 0.f;

#pragma unroll
        for (int co = 0; co < 8; ++co) {
#pragma unroll
            for (int ky = 0; ky < 3; ++ky)
#pragma unroll
                for (int kx = 0; kx < 3; ++kx) {
#pragma unroll
                    for (int q = 0; q < 4; ++q) {
                        unsigned int wv = wb[co * 36 + (ky * 3 + kx) * 4 + q];
#pragma unroll
                        for (int p = 0; p < 4; ++p)
                            acc[co][p] = dot2bf(vv[p + ky][kx][q], wv, acc[co][p]);
                    }
                }
        }

#pragma unroll
        for (int co = 0; co < 8; ++co) {
            int c = g * 8 + co;
            float mv = mod[i * 512 + b * 64 + c];
            __hip_bfloat16* op = bf + ((size_t)(i * 8 + b) * 64 + c) * 16384;
#pragma unroll
            for (int p = 0; p < 4; ++p) {
                int gh = tile_h0 + lr0 + p;
                op[gh * 128 + tile_w0 + lc] = __float2bfloat16(acc[co][p] * mv);
            }
        }
    }
}

// ---------------- Kernel 5 (v8): MFMA phase-1 + scalar epilogue ----------------
// grid 512 x 256. Block = 256 px; 4 waves x 4 Mtiles x 4 Ntiles, K=256.
__global__ void __launch_bounds__(256) k_mega(
    const float* __restrict__ x, const __hip_bfloat16* __restrict__ bfeat,
    const float* __restrict__ roi,
    const unsigned int* __restrict__ w1f, const float* __restrict__ dsh,
    const float* __restrict__ w2, const float* __restrict__ b2,
    const float* __restrict__ ew1,
    const float* __restrict__ ebnw, const float* __restrict__ ebnb,
    const float* __restrict__ ebnm, const float* __restrict__ ebnv,
    const float* __restrict__ ew2, const float* __restrict__ eb2,
    float* __restrict__ out) {

    __shared__ unsigned short y_lds[256 * 72];   // 36864 B, row = 144 B (16B-aligned)

    int tid = threadIdx.x;
    int p = blockIdx.x * 256 + tid;
    int b = p >> 14;
    int hw = p & 16383;
    int h = hw >> 7, w = hw & 127;
    int hw_base = (blockIdx.x & 63) * 256;

    const unsigned short* fbase = (const unsigned short*)bfeat;
    int l = tid & 63, wv = tid >> 6;
    int arow = l & 15, kg = l >> 4;

    // ---- phase 1: y = (w1*sc) @ feats_cat via MFMA 16x16x32 bf16 ----
    f32x4 acc[4][4];
#pragma unroll
    for (int mt = 0; mt < 4; ++mt)
#pragma unroll
        for (int nt = 0; nt < 4; ++nt)
            acc[mt][nt] = (f32x4){0.f, 0.f, 0.f, 0.f};

#pragma unroll 1
    for (int ks = 0; ks < 8; ++ks) {
        int k0 = ks * 32 + kg * 8;               // 8 consecutive k, same 64-block
        const unsigned short* cp = fbase
            + ((size_t)((k0 >> 6) * 512 + b * 64 + (k0 & 63))) * 16384 + hw_base;
        s8v af[4];
#pragma unroll
        for (int mt = 0; mt < 4; ++mt) {
            const unsigned short* q = cp + wv * 64 + mt * 16 + arow;
            unsigned int u0 = (unsigned int)q[0]         | ((unsigned int)q[16384]     << 16);
            unsigned int u1 = (unsigned int)q[2 * 16384] | ((unsigned int)q[3 * 16384] << 16);
            unsigned int u2 = (unsigned int)q[4 * 16384] | ((unsigned int)q[5 * 16384] << 16);
            unsigned int u3 = (unsigned int)q[6 * 16384] | ((unsigned int)q[7 * 16384] << 16);
            uint4v au; au.x = u0; au.y = u1; au.z = u2; au.w = u3;
            af[mt] = __builtin_bit_cast(s8v, au);
        }
        s8v bfr[4];
#pragma unroll
        for (int nt = 0; nt < 4; ++nt) {
            uint4v bu = *(const uint4v*)(w1f + (((nt * 8 + ks) * 64 + l) << 2));
            bfr[nt] = __builtin_bit_cast(s8v, bu);
        }
#pragma unroll
        for (int mt = 0; mt < 4; ++mt)
#pragma unroll
            for (int nt = 0; nt < 4; ++nt)
                acc[mt][nt] = __builtin_amdgcn_mfma_f32_16x16x32_bf16(
                    af[mt], bfr[nt], acc[mt][nt], 0, 0, 0);
    }

    // ---- scatter D fragments to LDS: px = wv*64+mt*16+(l>>4)*4+r, o = nt*16+(l&15) ----
#pragma unroll
    for (int mt = 0; mt < 4; ++mt)
#pragma unroll
        for (int nt = 0; nt < 4; ++nt)
#pragma unroll
            for (int r = 0; r < 4; ++r) {
                int px = wv * 64 + mt * 16 + kg * 4 + r;
                y_lds[px * 72 + nt * 16 + arow] = bf16bits(acc[mt][nt][r]);
            }
    __syncthreads();

    // ---- gather this thread's pixel, bias + relu ----
    float y[64];
    {
        const uint4v* yr = (const uint4v*)(y_lds + (size_t)tid * 72);
#pragma unroll
        for (int q8 = 0; q8 < 8; ++q8) {
            uint4v v = yr[q8];
            unsigned int e0 = v.x, e1 = v.y, e2 = v.z, e3 = v.w;
            y[q8 * 8 + 0] = __uint_as_float(e0 << 16);
            y[q8 * 8 + 1] = __uint_as_float(e0 & 0xffff0000u);
            y[q8 * 8 + 2] = __uint_as_float(e1 << 16);
            y[q8 * 8 + 3] = __uint_as_float(e1 & 0xffff0000u);
            y[q8 * 8 + 4] = __uint_as_float(e2 << 16);
            y[q8 * 8 + 5] = __uint_as_float(e2 & 0xffff0000u);
            y[q8 * 8 + 6] = __uint_as_float(e3 << 16);
            y[q8 * 8 + 7] = __uint_as_float(e3 & 0xffff0000u);
        }
    }
#pragma unroll
    for (int o = 0; o < 64; ++o) y[o] = fmaxf(y[o] + dsh[o], 0.f);

    const __hip_bfloat16* fb = bfeat + ((size_t)b * 64) * 16384 + hw;

    // ---- phase 2: logits + softmax ----
    float lg[4];
#pragma unroll
    for (int k = 0; k < 4; ++k) {
        float s = b2[k];
        const float* wr = w2 + k * 64;                   // uniform
#pragma unroll
        for (int o = 0; o < 64; ++o) s = fmaf(wr[o], y[o], s);
        lg[k] = s;
    }
    float mx = fmaxf(fmaxf(lg[0], lg[1]), fmaxf(lg[2], lg[3]));
    float e0 = expf(lg[0] - mx), e1s = expf(lg[1] - mx), e2s = expf(lg[2] - mx), e3s = expf(lg[3] - mx);
    float inv = 1.f / (e0 + e1s + e2s + e3s);
    float a0 = e0 * inv, a1 = e1s * inv, a2 = e2s * inv, a3 = e3s * inv;

    // ---- phase 3: roi bilinear (align_corners) ----
    float ysv = (float)h * (63.f / 127.f);
    float y0f = fminf(floorf(ysv), 62.f);
    float wy = ysv - y0f;
    float xsv = (float)w * (63.f / 127.f);
    float x0f = fminf(floorf(xsv), 62.f);
    float wx = xsv - x0f;
    int y0i = (int)y0f, x0i = (int)x0f;
    const float* rb = roi + (size_t)b * 4096;
    float r00 = rb[y0i * 64 + x0i], r01 = rb[y0i * 64 + x0i + 1];
    float r10 = rb[(y0i + 1) * 64 + x0i], r11 = rb[(y0i + 1) * 64 + x0i + 1];
    float rv = r00 * (1.f - wy) * (1.f - wx) + r01 * (1.f - wy) * wx
             + r10 * wy * (1.f - wx) + r11 * wy * wx;

    // ---- phase 4: fused = sum_i bf_i * attn_i, scaled by roi ----
    float f[64];
#pragma unroll
    for (int cc = 0; cc < 64; ++cc) {
        const __hip_bfloat16* pp = fb + (size_t)cc * 16384;
        float s = a0 * __bfloat162float(pp[0])
                + a1 * __bfloat162float(pp[(size_t)512 * 16384])
                + a2 * __bfloat162float(pp[(size_t)1024 * 16384])
                + a3 * __bfloat162float(pp[(size_t)1536 * 16384]);
        f[cc] = s * rv;
    }

    // ---- phase 5: edge MLP layer 1 + BN + relu ----
    float eh[32];
#pragma unroll
    for (int o = 0; o < 32; ++o) {
        float s = 0.f;
        const float* wr = ew1 + o * 64;                  // uniform
#pragma unroll
        for (int c = 0; c < 64; ++c) s = fmaf(wr[c], f[c], s);
        float sc = ebnw[o] * rsqrtf(ebnv[o] + 1e-5f);
        float sh = ebnb[o] - ebnm[o] * sc;
        eh[o] = fmaxf(fmaf(s, sc, sh), 0.f);
    }

    // ---- phase 6: e2 = sigmoid(ew2 @ eh + b), out = x*(1+e2) ----
    const float* xp = x + ((size_t)b * 64) * 16384 + hw;
    float* op = out + ((size_t)b * 64) * 16384 + hw;
#pragma unroll 4
    for (int cc = 0; cc < 64; ++cc) {
        float s = eb2[cc];
        const float* wr = ew2 + cc * 32;                 // uniform -> s_load
#pragma unroll
        for (int c = 0; c < 32; ++c) s = fmaf(wr[c], eh[c], s);
        float sg = 1.f / (1.f + expf(-s));
        float xv = xp[(size_t)cc * 16384];
        op[(size_t)cc * 16384] = xv + xv * sg;
    }
}

extern "C" void kernel_launch(void* const* d_in, const int* in_sizes, int n_in,
                              void* d_out, int out_size, void* d_ws, size_t ws_size,
                              hipStream_t stream) {
    const float* x    = (const float*)d_in[0];
    const float* roi  = (const float*)d_in[1];
    const float* bk   = (const float*)d_in[2];
    const float* aw1  = (const float*)d_in[3];
    const float* ab1  = (const float*)d_in[4];
    const float* aw2  = (const float*)d_in[5];
    const float* ab2  = (const float*)d_in[6];
    const float* mw1  = (const float*)d_in[7];
    const float* mb1  = (const float*)d_in[8];
    const float* mw2  = (const float*)d_in[9];
    const float* mb2  = (const float*)d_in[10];
    const float* w1   = (const float*)d_in[11];
    const float* bnw  = (const float*)d_in[12];
    const float* bnb  = (const float*)d_in[13];
    const float* bnm  = (const float*)d_in[14];
    const float* bnv  = (const float*)d_in[15];
    const float* w2   = (const float*)d_in[16];
    const float* b2   = (const float*)d_in[17];
    const float* ew1  = (const float*)d_in[18];
    const float* ebnw = (const float*)d_in[19];
    const float* ebnb = (const float*)d_in[20];
    const float* ebnm = (const float*)d_in[21];
    const float* ebnv = (const float*)d_in[22];
    const float* ew2  = (const float*)d_in[23];
    const float* eb2  = (const float*)d_in[24];

    float* ws     = (float*)d_ws;
    float* pooled = ws;                    // 512
    float* angles = ws + 512;              // 256
    float* mod    = ws + 768;              // 2048
    unsigned int* rotp = (unsigned int*)(ws + 2816);   // 73728 uints -> ends 76544
    unsigned int* w1f  = (unsigned int*)(ws + 150272); // 8192 uints (MFMA B-frags)
    float* dsh    = ws + 158464;           // 64
    __hip_bfloat16* bfeat = (__hip_bfloat16*)(ws + 166720);  // 64 MB

    k_prep<<<1, 256, 0, stream>>>(w1, bnw, bnb, bnm, bnv, w1f, dsh);
    k_pool<<<512, 256, 0, stream>>>(x, pooled);
    k_mlp<<<32, 64, 0, stream>>>(pooled, aw1, ab1, aw2, ab2, mw1, mb1, mw2, mb2, angles, mod);
    k_rot<<<256, 64, 0, stream>>>(bk, angles, rotp);
    k_conv<<<dim3(16, 64), 256, 0, stream>>>(x, rotp, mod, bfeat);
    k_mega<<<512, 256, 0, stream>>>(x, bfeat, roi, w1f, dsh, w2, b2,
                                    ew1, ebnw, ebnb, ebnm, ebnv, ew2, eb2,
                                    (float*)d_out);
}

// Round 11
// 151.662 us; speedup vs baseline: 3.5267x; 1.0971x over previous
//
#include <hip/hip_runtime.h>
#include <hip/hip_bf16.h>
#include <math.h>

#define PI4F 0.78539816339744830962f

typedef __attribute__((ext_vector_type(2))) __bf16 bf16x2_t;
typedef __attribute__((ext_vector_type(8))) short s8v;      // bf16x8 MFMA operand
typedef __attribute__((ext_vector_type(4))) float f32x4;    // MFMA accumulator
typedef __attribute__((ext_vector_type(4))) unsigned int uint4v;

__device__ __forceinline__ float dot2bf(unsigned int a, unsigned int b, float c) {
#if defined(__has_builtin) && __has_builtin(__builtin_amdgcn_fdot2_f32_bf16)
    return __builtin_amdgcn_fdot2_f32_bf16(__builtin_bit_cast(bf16x2_t, a),
                                           __builtin_bit_cast(bf16x2_t, b), c, false);
#else
    float a0 = __uint_as_float(a << 16), a1 = __uint_as_float(a & 0xffff0000u);
    float b0 = __uint_as_float(b << 16), b1 = __uint_as_float(b & 0xffff0000u);
    return fmaf(a1, b1, fmaf(a0, b0, c));
#endif
}

__device__ __forceinline__ unsigned short bf16bits(float v) {
    return __builtin_bit_cast(unsigned short, __float2bfloat16(v));
}
__device__ __forceinline__ unsigned int packbf(float lo, float hi) {
    return (unsigned int)bf16bits(lo) | ((unsigned int)bf16bits(hi) << 16);
}

// ---------------- Kernel 1: global average pool (float4) ----------------
__global__ void k_pool(const float* __restrict__ x, float* __restrict__ pooled) {
    int bc = blockIdx.x;
    const float4* p4 = (const float4*)(x + (size_t)bc * 16384);
    float s = 0.f;
    for (int j = threadIdx.x; j < 4096; j += 256) {
        float4 v = p4[j];
        s += (v.x + v.y) + (v.z + v.w);
    }
    for (int off = 32; off > 0; off >>= 1) s += __shfl_xor(s, off, 64);
    __shared__ float red[4];
    int wave = threadIdx.x >> 6;
    if ((threadIdx.x & 63) == 0) red[wave] = s;
    __syncthreads();
    if (threadIdx.x == 0) {
        float t = red[0] + red[1] + red[2] + red[3];
        pooled[bc] = t * (1.0f / 16384.0f);
    }
}

// ---------------- Kernel 2: small MLPs -> angles, mod ----------------
__global__ void k_mlp(const float* __restrict__ pooled,
                      const float* __restrict__ aw1, const float* __restrict__ ab1,
                      const float* __restrict__ aw2, const float* __restrict__ ab2,
                      const float* __restrict__ mw1, const float* __restrict__ mb1,
                      const float* __restrict__ mw2, const float* __restrict__ mb2,
                      float* __restrict__ angles, float* __restrict__ mod) {
    int i = blockIdx.x >> 3, b = blockIdx.x & 7;
    int t = threadIdx.x;
    __shared__ float sp[64], sha[16], shm[16];
    sp[t] = pooled[b * 64 + t];
    __syncthreads();
    if (t < 16) {
        float sa = ab1[i * 16 + t], sm = mb1[i * 16 + t];
        const float* wa = aw1 + ((size_t)i * 16 + t) * 64;
        const float* wm = mw1 + ((size_t)i * 16 + t) * 64;
        for (int c = 0; c < 64; ++c) { sa = fmaf(wa[c], sp[c], sa); sm = fmaf(wm[c], sp[c], sm); }
        sha[t] = fmaxf(sa, 0.f);
        shm[t] = fmaxf(sm, 0.f);
    }
    __syncthreads();
    if (t < 8) {
        float s = ab2[i * 8 + t];
        const float* w = aw2 + ((size_t)i * 8 + t) * 16;
        for (int j = 0; j < 16; ++j) s = fmaf(w[j], sha[j], s);
        angles[i * 64 + b * 8 + t] = tanhf(s) * PI4F;
    }
    {
        float s = mb2[i * 64 + t];
        const float* w = mw2 + ((size_t)i * 64 + t) * 16;
        for (int j = 0; j < 16; ++j) s = fmaf(w[j], shm[j], s);
        mod[i * 512 + b * 64 + t] = 1.f / (1.f + expf(-s));
    }
}

// ---------------- Kernel 3 (v2): rotate base kernels -> bf16 pair-packed ----------------
__global__ void k_rot(const float* __restrict__ bk, const float* __restrict__ angles,
                      unsigned int* __restrict__ rotp) {
    int blk = blockIdx.x;
    int g = blk & 7, b = (blk >> 3) & 7, i = blk >> 6;
    float ang = angles[i * 64 + b * 8 + g];
    float st, ct;
    sincosf(ang, &st, &ct);
    int t = threadIdx.x;
    int co = t >> 3, ci = t & 7;
    const float* K = bk + ((((size_t)i * 8 + g) * 8 + co) * 8 + ci) * 9;
    __shared__ float tmp[576];
#pragma unroll
    for (int p = 0; p < 9; ++p) {
        int ky = p / 3, kx = p % 3;
        float xx = (float)kx - 1.f, yy = (float)ky - 1.f;
        float xr = xx * ct + yy * st + 1.f;
        float yr = -xx * st + yy * ct + 1.f;
        float x0 = fminf(fmaxf(floorf(xr), 0.f), 1.f);
        float y0 = fminf(fmaxf(floorf(yr), 0.f), 1.f);
        float x1 = x0 + 1.f, y1 = y0 + 1.f;
        float w00 = (x1 - xr) * (y1 - yr);
        float w01 = (x1 - xr) * (yr - y0);
        float w10 = (xr - x0) * (y1 - yr);
        float w11 = (xr - x0) * (yr - y0);
        int x0i = (int)x0, y0i = (int)y0;
        float v = w00 * K[y0i * 3 + x0i] + w01 * K[(y0i + 1) * 3 + x0i]
                + w10 * K[y0i * 3 + x0i + 1] + w11 * K[(y0i + 1) * 3 + x0i + 1];
        tmp[t * 9 + p] = v;
    }
    __syncthreads();
    unsigned int* R = rotp + (size_t)blk * 288;
    for (int ot = t; ot < 288; ot += 64) {
        int co2 = ot / 36;
        int rem = ot - co2 * 36;
        int pos = rem >> 2;
        int q = rem & 3;
        float v0 = tmp[(co2 * 8 + 2 * q) * 9 + pos];
        float v1 = tmp[(co2 * 8 + 2 * q + 1) * 9 + pos];
        R[ot] = packbf(v0, v1);
    }
}

// ---------------- Kernel 3.5: prep (w1 MFMA-frags; ew1/ew2 bf16-pairs) ----------------
__global__ void k_prep(const float* __restrict__ w1,
                       const float* __restrict__ bnw, const float* __restrict__ bnb,
                       const float* __restrict__ bnm, const float* __restrict__ bnv,
                       const float* __restrict__ ew1,
                       const float* __restrict__ ebnw, const float* __restrict__ ebnb,
                       const float* __restrict__ ebnm, const float* __restrict__ ebnv,
                       const float* __restrict__ ew2,
                       unsigned int* __restrict__ w1f, float* __restrict__ dsh,
                       unsigned int* __restrict__ ew1p, float* __restrict__ esh,
                       unsigned int* __restrict__ ew2p) {
    int tid = threadIdx.x;
    __shared__ float sc[64], sce[32];
    if (tid < 64) {
        float s = bnw[tid] * rsqrtf(bnv[tid] + 1e-5f);
        sc[tid] = s;
        dsh[tid] = bnb[tid] - bnm[tid] * s;
    }
    if (tid < 32) {
        float s = ebnw[tid] * rsqrtf(ebnv[tid] + 1e-5f);
        sce[tid] = s;
        esh[tid] = ebnb[tid] - ebnm[tid] * s;
    }
    __syncthreads();
    // w1 -> MFMA B-fragment order with dir-BN scale folded
    for (int q = tid; q < 8192; q += 256) {
        int jp = q & 3;
        int l  = (q >> 2) & 63;
        int ks = (q >> 8) & 7;
        int nt = q >> 11;
        int o = nt * 16 + (l & 15);
        int k = ks * 32 + (l >> 4) * 8 + jp * 2;
        w1f[q] = packbf(w1[o * 256 + k] * sc[o], w1[o * 256 + k + 1] * sc[o]);
    }
    // ew1*sce -> pairs [o][q], 32x32
    for (int q = tid; q < 1024; q += 256) {
        int o = q >> 5, c2 = q & 31;
        ew1p[q] = packbf(ew1[o * 64 + 2 * c2] * sce[o], ew1[o * 64 + 2 * c2 + 1] * sce[o]);
    }
    // ew2 -> pairs [cc][q], 64x16
    for (int q = tid; q < 1024; q += 256) {
        int cc = q >> 4, c2 = q & 15;
        ew2p[q] = packbf(ew2[cc * 32 + 2 * c2], ew2[cc * 32 + 2 * c2 + 1]);
    }
}

// ---------------- Kernel 4 (v8): 16x16 tiles, 1 px/thread, high occupancy ----------------
// grid (64, 64) = (tile, b*8+g); block 256. LDS 6.5 KB.
__global__ void __launch_bounds__(256) k_conv(const float* __restrict__ x,
                       const unsigned int* __restrict__ rotp, const float* __restrict__ mod,
                       __hip_bfloat16* __restrict__ bf) {
    __shared__ unsigned int s_in[324 * 5];      // 6480 B
    unsigned short* s16 = (unsigned short*)s_in;

    int bg = blockIdx.y;
    int b = bg >> 3, g = bg & 7;
    int tile_h0 = (blockIdx.x >> 3) * 16;
    int tile_w0 = (blockIdx.x & 7) * 16;
    int tid = threadIdx.x;

    const float* xg = x + ((size_t)b * 64 + (size_t)g * 8) * 16384;
    for (int idx = tid; idx < 8 * 324; idx += 256) {
        int ci = idx / 324;
        int pix = idx - ci * 324;
        int r = pix / 18;
        int c = pix - r * 18;
        int gh = tile_h0 + r - 1;
        int gw = tile_w0 + c - 1;
        float v = 0.f;
        if (gh >= 0 && gh < 128 && gw >= 0 && gw < 128)
            v = xg[(size_t)ci * 16384 + gh * 128 + gw];
        s16[pix * 10 + ci] = bf16bits(v);
    }
    __syncthreads();

    int lc = tid & 15;
    int lr = tid >> 4;

    // 3x3 neighborhood, all 8 ci packed in 4 dwords/pixel
    unsigned int vv[3][3][4];
#pragma unroll
    for (int r = 0; r < 3; ++r)
#pragma unroll
        for (int c = 0; c < 3; ++c) {
            int pix = (lr + r) * 18 + lc + c;
#pragma unroll
            for (int q = 0; q < 4; ++q)
                vv[r][c][q] = s_in[pix * 5 + q];
        }

#pragma unroll 1
    for (int i = 0; i < 4; ++i) {
        const unsigned int* wb = rotp + ((size_t)(i * 8 + b) * 8 + g) * 288;  // uniform -> s_load

        float acc[8];
#pragma unroll
        for (int co = 0; co < 8; ++co) acc[co] = 0.f;

#pragma unroll
        for (int co = 0; co < 8; ++co)
#pragma unroll
            for (int ky = 0; ky < 3; ++ky)
#pragma unroll
                for (int kx = 0; kx < 3; ++kx)
#pragma unroll
                    for (int q = 0; q < 4; ++q)
                        acc[co] = dot2bf(vv[ky][kx][q],
                                         wb[co * 36 + (ky * 3 + kx) * 4 + q], acc[co]);

#pragma unroll
        for (int co = 0; co < 8; ++co) {
            int c = g * 8 + co;
            float mv = mod[i * 512 + b * 64 + c];
            __hip_bfloat16* op = bf + ((size_t)(i * 8 + b) * 64 + c) * 16384;
            op[(tile_h0 + lr) * 128 + tile_w0 + lc] = __float2bfloat16(acc[co] * mv);
        }
    }
}

// ---------------- Kernel 5 (v9): MFMA phase-1 + dot2 epilogue ----------------
// grid 512 x 256. Block = 256 px; 4 waves x 4 Mtiles x 4 Ntiles, K=256.
__global__ void __launch_bounds__(256) k_mega(
    const float* __restrict__ x, const __hip_bfloat16* __restrict__ bfeat,
    const float* __restrict__ roi,
    const unsigned int* __restrict__ w1f, const float* __restrict__ dsh,
    const float* __restrict__ w2, const float* __restrict__ b2,
    const unsigned int* __restrict__ ew1p, const float* __restrict__ esh,
    const unsigned int* __restrict__ ew2p, const float* __restrict__ eb2,
    float* __restrict__ out) {

    __shared__ unsigned short y_lds[256 * 72];   // 36864 B

    int tid = threadIdx.x;
    int p = blockIdx.x * 256 + tid;
    int b = p >> 14;
    int hw = p & 16383;
    int h = hw >> 7, w = hw & 127;
    int hw_base = (blockIdx.x & 63) * 256;

    const unsigned short* fbase = (const unsigned short*)bfeat;
    int l = tid & 63, wv = tid >> 6;
    int arow = l & 15, kg = l >> 4;

    // ---- phase 1: y = (w1*sc) @ feats_cat via MFMA 16x16x32 bf16 ----
    f32x4 acc[4][4];
#pragma unroll
    for (int mt = 0; mt < 4; ++mt)
#pragma unroll
        for (int nt = 0; nt < 4; ++nt)
            acc[mt][nt] = (f32x4){0.f, 0.f, 0.f, 0.f};

#pragma unroll 1
    for (int ks = 0; ks < 8; ++ks) {
        int k0 = ks * 32 + kg * 8;
        const unsigned short* cp = fbase
            + ((size_t)((k0 >> 6) * 512 + b * 64 + (k0 & 63))) * 16384 + hw_base;
        s8v af[4];
#pragma unroll
        for (int mt = 0; mt < 4; ++mt) {
            const unsigned short* q = cp + wv * 64 + mt * 16 + arow;
            unsigned int u0 = (unsigned int)q[0]         | ((unsigned int)q[16384]     << 16);
            unsigned int u1 = (unsigned int)q[2 * 16384] | ((unsigned int)q[3 * 16384] << 16);
            unsigned int u2 = (unsigned int)q[4 * 16384] | ((unsigned int)q[5 * 16384] << 16);
            unsigned int u3 = (unsigned int)q[6 * 16384] | ((unsigned int)q[7 * 16384] << 16);
            uint4v au; au.x = u0; au.y = u1; au.z = u2; au.w = u3;
            af[mt] = __builtin_bit_cast(s8v, au);
        }
        s8v bfr[4];
#pragma unroll
        for (int nt = 0; nt < 4; ++nt) {
            uint4v bu = *(const uint4v*)(w1f + (((nt * 8 + ks) * 64 + l) << 2));
            bfr[nt] = __builtin_bit_cast(s8v, bu);
        }
#pragma unroll
        for (int mt = 0; mt < 4; ++mt)
#pragma unroll
            for (int nt = 0; nt < 4; ++nt)
                acc[mt][nt] = __builtin_amdgcn_mfma_f32_16x16x32_bf16(
                    af[mt], bfr[nt], acc[mt][nt], 0, 0, 0);
    }

    // ---- scatter D fragments to LDS ----
#pragma unroll
    for (int mt = 0; mt < 4; ++mt)
#pragma unroll
        for (int nt = 0; nt < 4; ++nt)
#pragma unroll
            for (int r = 0; r < 4; ++r) {
                int px = wv * 64 + mt * 16 + kg * 4 + r;
                y_lds[px * 72 + nt * 16 + arow] = bf16bits(acc[mt][nt][r]);
            }
    __syncthreads();

    // ---- gather this thread's pixel, bias + relu ----
    float y[64];
    {
        const uint4v* yr = (const uint4v*)(y_lds + (size_t)tid * 72);
#pragma unroll
        for (int q8 = 0; q8 < 8; ++q8) {
            uint4v v = yr[q8];
            y[q8 * 8 + 0] = __uint_as_float(v.x << 16);
            y[q8 * 8 + 1] = __uint_as_float(v.x & 0xffff0000u);
            y[q8 * 8 + 2] = __uint_as_float(v.y << 16);
            y[q8 * 8 + 3] = __uint_as_float(v.y & 0xffff0000u);
            y[q8 * 8 + 4] = __uint_as_float(v.z << 16);
            y[q8 * 8 + 5] = __uint_as_float(v.z & 0xffff0000u);
            y[q8 * 8 + 6] = __uint_as_float(v.w << 16);
            y[q8 * 8 + 7] = __uint_as_float(v.w & 0xffff0000u);
        }
    }
#pragma unroll
    for (int o = 0; o < 64; ++o) y[o] = fmaxf(y[o] + dsh[o], 0.f);

    const unsigned short* fbu = fbase + ((size_t)b * 64) * 16384 + hw;

    // ---- phase 2: logits + softmax ----
    float lg[4];
#pragma unroll
    for (int k = 0; k < 4; ++k) {
        float s = b2[k];
        const float* wr = w2 + k * 64;                   // uniform
#pragma unroll
        for (int o = 0; o < 64; ++o) s = fmaf(wr[o], y[o], s);
        lg[k] = s;
    }
    float mx = fmaxf(fmaxf(lg[0], lg[1]), fmaxf(lg[2], lg[3]));
    float e0 = expf(lg[0] - mx), e1s = expf(lg[1] - mx), e2s = expf(lg[2] - mx), e3s = expf(lg[3] - mx);
    float inv = 1.f / (e0 + e1s + e2s + e3s);

    // ---- phase 3: roi bilinear (align_corners) ----
    float ysv = (float)h * (63.f / 127.f);
    float y0f = fminf(floorf(ysv), 62.f);
    float wy = ysv - y0f;
    float xsv = (float)w * (63.f / 127.f);
    float x0f = fminf(floorf(xsv), 62.f);
    float wx = xsv - x0f;
    int y0i = (int)y0f, x0i = (int)x0f;
    const float* rb = roi + (size_t)b * 4096;
    float r00 = rb[y0i * 64 + x0i], r01 = rb[y0i * 64 + x0i + 1];
    float r10 = rb[(y0i + 1) * 64 + x0i], r11 = rb[(y0i + 1) * 64 + x0i + 1];
    float rv = r00 * (1.f - wy) * (1.f - wx) + r01 * (1.f - wy) * wx
             + r10 * wy * (1.f - wx) + r11 * wy * wx;

    // fold rv into attention weights, pack as bf16 pairs
    float ar = inv * rv;
    unsigned int pa01 = packbf(e0 * ar, e1s * ar);
    unsigned int pa23 = packbf(e2s * ar, e3s * ar);

    // ---- phase 4: f = sum_i bf_i * (attn_i*rv), via dot2 ----
    float f[64];
#pragma unroll
    for (int cc = 0; cc < 64; ++cc) {
        const unsigned short* pp = fbu + (size_t)cc * 16384;
        unsigned int u01 = (unsigned int)pp[0]
                         | ((unsigned int)pp[(size_t)512 * 16384] << 16);
        unsigned int u23 = (unsigned int)pp[(size_t)1024 * 16384]
                         | ((unsigned int)pp[(size_t)1536 * 16384] << 16);
        f[cc] = dot2bf(u23, pa23, dot2bf(u01, pa01, 0.f));
    }
    unsigned int fpk[32];
#pragma unroll
    for (int q = 0; q < 32; ++q) fpk[q] = packbf(f[2 * q], f[2 * q + 1]);

    // ---- phase 5: edge MLP layer 1 via dot2 (BN scale folded) + relu ----
    float eh[32];
#pragma unroll
    for (int o = 0; o < 32; ++o) {
        float s = 0.f;
        const unsigned int* wr = ew1p + o * 32;          // uniform -> SGPR
#pragma unroll
        for (int q = 0; q < 32; ++q) s = dot2bf(fpk[q], wr[q], s);
        eh[o] = fmaxf(s + esh[o], 0.f);
    }
    unsigned int ehp[16];
#pragma unroll
    for (int q = 0; q < 16; ++q) ehp[q] = packbf(eh[2 * q], eh[2 * q + 1]);

    // ---- phase 6: e2 = sigmoid(ew2 @ eh + b), out = x*(1+e2) ----
    const float* xp = x + ((size_t)b * 64) * 16384 + hw;
    float* op = out + ((size_t)b * 64) * 16384 + hw;
#pragma unroll 4
    for (int cc = 0; cc < 64; ++cc) {
        float s = eb2[cc];
        const unsigned int* wr = ew2p + cc * 16;         // uniform -> SGPR
#pragma unroll
        for (int q = 0; q < 16; ++q) s = dot2bf(ehp[q], wr[q], s);
        float sg = 1.f / (1.f + expf(-s));
        float xv = xp[(size_t)cc * 16384];
        op[(size_t)cc * 16384] = xv + xv * sg;
    }
}

extern "C" void kernel_launch(void* const* d_in, const int* in_sizes, int n_in,
                              void* d_out, int out_size, void* d_ws, size_t ws_size,
                              hipStream_t stream) {
    const float* x    = (const float*)d_in[0];
    const float* roi  = (const float*)d_in[1];
    const float* bk   = (const float*)d_in[2];
    const float* aw1  = (const float*)d_in[3];
    const float* ab1  = (const float*)d_in[4];
    const float* aw2  = (const float*)d_in[5];
    const float* ab2  = (const float*)d_in[6];
    const float* mw1  = (const float*)d_in[7];
    const float* mb1  = (const float*)d_in[8];
    const float* mw2  = (const float*)d_in[9];
    const float* mb2  = (const float*)d_in[10];
    const float* w1   = (const float*)d_in[11];
    const float* bnw  = (const float*)d_in[12];
    const float* bnb  = (const float*)d_in[13];
    const float* bnm  = (const float*)d_in[14];
    const float* bnv  = (const float*)d_in[15];
    const float* w2   = (const float*)d_in[16];
    const float* b2   = (const float*)d_in[17];
    const float* ew1  = (const float*)d_in[18];
    const float* ebnw = (const float*)d_in[19];
    const float* ebnb = (const float*)d_in[20];
    const float* ebnm = (const float*)d_in[21];
    const float* ebnv = (const float*)d_in[22];
    const float* ew2  = (const float*)d_in[23];
    const float* eb2  = (const float*)d_in[24];

    float* ws     = (float*)d_ws;
    float* pooled = ws;                    // 512
    float* angles = ws + 512;              // 256
    float* mod    = ws + 768;              // 2048
    unsigned int* rotp = (unsigned int*)(ws + 2816);   // 73728 uints
    unsigned int* w1f  = (unsigned int*)(ws + 150272); // 8192 uints (MFMA B-frags)
    float* dsh    = ws + 158464;           // 64
    unsigned int* ew1p = (unsigned int*)(ws + 158528); // 1024
    float* esh    = ws + 159552;           // 32
    unsigned int* ew2p = (unsigned int*)(ws + 159584); // 1024
    __hip_bfloat16* bfeat = (__hip_bfloat16*)(ws + 166720);  // 64 MB

    k_prep<<<1, 256, 0, stream>>>(w1, bnw, bnb, bnm, bnv,
                                  ew1, ebnw, ebnb, ebnm, ebnv, ew2,
                                  w1f, dsh, ew1p, esh, ew2p);
    k_pool<<<512, 256, 0, stream>>>(x, pooled);
    k_mlp<<<32, 64, 0, stream>>>(pooled, aw1, ab1, aw2, ab2, mw1, mb1, mw2, mb2, angles, mod);
    k_rot<<<256, 64, 0, stream>>>(bk, angles, rotp);
    k_conv<<<dim3(64, 64), 256, 0, stream>>>(x, rotp, mod, bfeat);
    k_mega<<<512, 256, 0, stream>>>(x, bfeat, roi, w1f, dsh, w2, b2,
                                    ew1p, esh, ew2p, eb2,
                                    (float*)d_out);
}

// Round 12
// 144.120 us; speedup vs baseline: 3.7112x; 1.0523x over previous
//
#include <hip/hip_runtime.h>
#include <hip/hip_bf16.h>
#include <math.h>

#define PI4F 0.78539816339744830962f

typedef __attribute__((ext_vector_type(2))) __bf16 bf16x2_t;
typedef __attribute__((ext_vector_type(8))) short s8v;      // bf16x8 MFMA operand
typedef __attribute__((ext_vector_type(4))) float f32x4;    // MFMA accumulator
typedef __attribute__((ext_vector_type(4))) unsigned int uint4v;

__device__ __forceinline__ float dot2bf(unsigned int a, unsigned int b, float c) {
#if defined(__has_builtin) && __has_builtin(__builtin_amdgcn_fdot2_f32_bf16)
    return __builtin_amdgcn_fdot2_f32_bf16(__builtin_bit_cast(bf16x2_t, a),
                                           __builtin_bit_cast(bf16x2_t, b), c, false);
#else
    float a0 = __uint_as_float(a << 16), a1 = __uint_as_float(a & 0xffff0000u);
    float b0 = __uint_as_float(b << 16), b1 = __uint_as_float(b & 0xffff0000u);
    return fmaf(a1, b1, fmaf(a0, b0, c));
#endif
}

__device__ __forceinline__ unsigned short bf16bits(float v) {
    return __builtin_bit_cast(unsigned short, __float2bfloat16(v));
}
__device__ __forceinline__ unsigned int packbf(float lo, float hi) {
    return (unsigned int)bf16bits(lo) | ((unsigned int)bf16bits(hi) << 16);
}

// ---------------- Kernel 1: global average pool (float4) ----------------
__global__ void k_pool(const float* __restrict__ x, float* __restrict__ pooled) {
    int bc = blockIdx.x;
    const float4* p4 = (const float4*)(x + (size_t)bc * 16384);
    float s = 0.f;
    for (int j = threadIdx.x; j < 4096; j += 256) {
        float4 v = p4[j];
        s += (v.x + v.y) + (v.z + v.w);
    }
    for (int off = 32; off > 0; off >>= 1) s += __shfl_xor(s, off, 64);
    __shared__ float red[4];
    int wave = threadIdx.x >> 6;
    if ((threadIdx.x & 63) == 0) red[wave] = s;
    __syncthreads();
    if (threadIdx.x == 0) {
        float t = red[0] + red[1] + red[2] + red[3];
        pooled[bc] = t * (1.0f / 16384.0f);
    }
}

// ---------------- Kernel 2: small MLPs -> angles, mod ----------------
__global__ void k_mlp(const float* __restrict__ pooled,
                      const float* __restrict__ aw1, const float* __restrict__ ab1,
                      const float* __restrict__ aw2, const float* __restrict__ ab2,
                      const float* __restrict__ mw1, const float* __restrict__ mb1,
                      const float* __restrict__ mw2, const float* __restrict__ mb2,
                      float* __restrict__ angles, float* __restrict__ mod) {
    int i = blockIdx.x >> 3, b = blockIdx.x & 7;
    int t = threadIdx.x;
    __shared__ float sp[64], sha[16], shm[16];
    sp[t] = pooled[b * 64 + t];
    __syncthreads();
    if (t < 16) {
        float sa = ab1[i * 16 + t], sm = mb1[i * 16 + t];
        const float* wa = aw1 + ((size_t)i * 16 + t) * 64;
        const float* wm = mw1 + ((size_t)i * 16 + t) * 64;
        for (int c = 0; c < 64; ++c) { sa = fmaf(wa[c], sp[c], sa); sm = fmaf(wm[c], sp[c], sm); }
        sha[t] = fmaxf(sa, 0.f);
        shm[t] = fmaxf(sm, 0.f);
    }
    __syncthreads();
    if (t < 8) {
        float s = ab2[i * 8 + t];
        const float* w = aw2 + ((size_t)i * 8 + t) * 16;
        for (int j = 0; j < 16; ++j) s = fmaf(w[j], sha[j], s);
        angles[i * 64 + b * 8 + t] = tanhf(s) * PI4F;
    }
    {
        float s = mb2[i * 64 + t];
        const float* w = mw2 + ((size_t)i * 64 + t) * 16;
        for (int j = 0; j < 16; ++j) s = fmaf(w[j], shm[j], s);
        mod[i * 512 + b * 64 + t] = 1.f / (1.f + expf(-s));
    }
}

// ---------------- Kernel 3 (v2): rotate base kernels -> bf16 pair-packed ----------------
__global__ void k_rot(const float* __restrict__ bk, const float* __restrict__ angles,
                      unsigned int* __restrict__ rotp) {
    int blk = blockIdx.x;
    int g = blk & 7, b = (blk >> 3) & 7, i = blk >> 6;
    float ang = angles[i * 64 + b * 8 + g];
    float st, ct;
    sincosf(ang, &st, &ct);
    int t = threadIdx.x;
    int co = t >> 3, ci = t & 7;
    const float* K = bk + ((((size_t)i * 8 + g) * 8 + co) * 8 + ci) * 9;
    __shared__ float tmp[576];
#pragma unroll
    for (int p = 0; p < 9; ++p) {
        int ky = p / 3, kx = p % 3;
        float xx = (float)kx - 1.f, yy = (float)ky - 1.f;
        float xr = xx * ct + yy * st + 1.f;
        float yr = -xx * st + yy * ct + 1.f;
        float x0 = fminf(fmaxf(floorf(xr), 0.f), 1.f);
        float y0 = fminf(fmaxf(floorf(yr), 0.f), 1.f);
        float x1 = x0 + 1.f, y1 = y0 + 1.f;
        float w00 = (x1 - xr) * (y1 - yr);
        float w01 = (x1 - xr) * (yr - y0);
        float w10 = (xr - x0) * (y1 - yr);
        float w11 = (xr - x0) * (yr - y0);
        int x0i = (int)x0, y0i = (int)y0;
        float v = w00 * K[y0i * 3 + x0i] + w01 * K[(y0i + 1) * 3 + x0i]
                + w10 * K[y0i * 3 + x0i + 1] + w11 * K[(y0i + 1) * 3 + x0i + 1];
        tmp[t * 9 + p] = v;
    }
    __syncthreads();
    unsigned int* R = rotp + (size_t)blk * 288;
    for (int ot = t; ot < 288; ot += 64) {
        int co2 = ot / 36;
        int rem = ot - co2 * 36;
        int pos = rem >> 2;
        int q = rem & 3;
        float v0 = tmp[(co2 * 8 + 2 * q) * 9 + pos];
        float v1 = tmp[(co2 * 8 + 2 * q + 1) * 9 + pos];
        R[ot] = packbf(v0, v1);
    }
}

// ---------------- Kernel 3.5: prep (w1 MFMA-frags; ew1/ew2 bf16-pairs) ----------------
__global__ void k_prep(const float* __restrict__ w1,
                       const float* __restrict__ bnw, const float* __restrict__ bnb,
                       const float* __restrict__ bnm, const float* __restrict__ bnv,
                       const float* __restrict__ ew1,
                       const float* __restrict__ ebnw, const float* __restrict__ ebnb,
                       const float* __restrict__ ebnm, const float* __restrict__ ebnv,
                       const float* __restrict__ ew2,
                       unsigned int* __restrict__ w1f, float* __restrict__ dsh,
                       unsigned int* __restrict__ ew1p, float* __restrict__ esh,
                       unsigned int* __restrict__ ew2p) {
    int tid = threadIdx.x;
    __shared__ float sc[64], sce[32];
    if (tid < 64) {
        float s = bnw[tid] * rsqrtf(bnv[tid] + 1e-5f);
        sc[tid] = s;
        dsh[tid] = bnb[tid] - bnm[tid] * s;
    }
    if (tid < 32) {
        float s = ebnw[tid] * rsqrtf(ebnv[tid] + 1e-5f);
        sce[tid] = s;
        esh[tid] = ebnb[tid] - ebnm[tid] * s;
    }
    __syncthreads();
    for (int q = tid; q < 8192; q += 256) {
        int jp = q & 3;
        int l  = (q >> 2) & 63;
        int ks = (q >> 8) & 7;
        int nt = q >> 11;
        int o = nt * 16 + (l & 15);
        int k = ks * 32 + (l >> 4) * 8 + jp * 2;
        w1f[q] = packbf(w1[o * 256 + k] * sc[o], w1[o * 256 + k + 1] * sc[o]);
    }
    for (int q = tid; q < 1024; q += 256) {
        int o = q >> 5, c2 = q & 31;
        ew1p[q] = packbf(ew1[o * 64 + 2 * c2] * sce[o], ew1[o * 64 + 2 * c2 + 1] * sce[o]);
    }
    for (int q = tid; q < 1024; q += 256) {
        int cc = q >> 4, c2 = q & 15;
        ew2p[q] = packbf(ew2[cc * 32 + 2 * c2], ew2[cc * 32 + 2 * c2 + 1]);
    }
}

// ---------------- Kernel 4 (v9): 32x32 tiles, dot2, branch loop unroll-2 ----------------
// grid (16, 64) = (tile, b*8+g); block 256. LDS 23 KB, conflict-free stride-5.
__global__ void __launch_bounds__(256) k_conv(const float* __restrict__ x,
                       const unsigned int* __restrict__ rotp, const float* __restrict__ mod,
                       __hip_bfloat16* __restrict__ bf) {
    __shared__ unsigned int s_in[1156 * 5];     // 23120 B
    unsigned short* s16 = (unsigned short*)s_in;

    int bg = blockIdx.y;
    int b = bg >> 3, g = bg & 7;
    int tile_h0 = (blockIdx.x >> 2) * 32;
    int tile_w0 = (blockIdx.x & 3) * 32;
    int tid = threadIdx.x;

    const float* xg = x + ((size_t)b * 64 + (size_t)g * 8) * 16384;
    for (int idx = tid; idx < 8 * 1156; idx += 256) {
        int ci = idx / 1156;
        int pix = idx - ci * 1156;
        int r = pix / 34;
        int c = pix - r * 34;
        int gh = tile_h0 + r - 1;
        int gw = tile_w0 + c - 1;
        float v = 0.f;
        if (gh >= 0 && gh < 128 && gw >= 0 && gw < 128)
            v = xg[(size_t)ci * 16384 + gh * 128 + gw];
        s16[pix * 10 + ci] = bf16bits(v);
    }
    __syncthreads();

    int lc = tid & 31;
    int lr0 = (tid >> 5) * 4;

    // 6x3 neighborhood read ONCE (all 8 ci packed), reused across 4 branches
    unsigned int vv[6][3][4];
#pragma unroll
    for (int r = 0; r < 6; ++r)
#pragma unroll
        for (int c = 0; c < 3; ++c) {
            int pix = (lr0 + r) * 34 + lc + c;
#pragma unroll
            for (int q = 0; q < 4; ++q)
                vv[r][c][q] = s_in[pix * 5 + q];
        }

#pragma unroll 2      // software-pipeline weight s_loads across branch pairs
    for (int i = 0; i < 4; ++i) {
        const unsigned int* wb = rotp + ((size_t)(i * 8 + b) * 8 + g) * 288;  // uniform -> s_load

        float acc[8][4];
#pragma unroll
        for (int co = 0; co < 8; ++co)
#pragma unroll
            for (int p = 0; p < 4; ++p) acc[co][p] = 0.f;

#pragma unroll
        for (int co = 0; co < 8; ++co)
#pragma unroll
            for (int ky = 0; ky < 3; ++ky)
#pragma unroll
                for (int kx = 0; kx < 3; ++kx)
#pragma unroll
                    for (int q = 0; q < 4; ++q) {
                        unsigned int wv = wb[co * 36 + (ky * 3 + kx) * 4 + q];
#pragma unroll
                        for (int p = 0; p < 4; ++p)
                            acc[co][p] = dot2bf(vv[p + ky][kx][q], wv, acc[co][p]);
                    }

#pragma unroll
        for (int co = 0; co < 8; ++co) {
            int c = g * 8 + co;
            float mv = mod[i * 512 + b * 64 + c];
            __hip_bfloat16* op = bf + ((size_t)(i * 8 + b) * 64 + c) * 16384;
#pragma unroll
            for (int p = 0; p < 4; ++p) {
                int gh = tile_h0 + lr0 + p;
                op[gh * 128 + tile_w0 + lc] = __float2bfloat16(acc[co][p] * mv);
            }
        }
    }
}

// ---------------- Kernel 5 (v10): MFMA phase-1 + dot2 epilogue, deep ILP ----------------
// grid 512 x 256. Block = 256 px; 4 waves x 4 Mtiles x 4 Ntiles, K=256.
__global__ void __launch_bounds__(256) k_mega(
    const float* __restrict__ x, const __hip_bfloat16* __restrict__ bfeat,
    const float* __restrict__ roi,
    const unsigned int* __restrict__ w1f, const float* __restrict__ dsh,
    const float* __restrict__ w2, const float* __restrict__ b2,
    const unsigned int* __restrict__ ew1p, const float* __restrict__ esh,
    const unsigned int* __restrict__ ew2p, const float* __restrict__ eb2,
    float* __restrict__ out) {

    __shared__ unsigned short y_lds[256 * 72];   // 36864 B

    int tid = threadIdx.x;
    int p = blockIdx.x * 256 + tid;
    int b = p >> 14;
    int hw = p & 16383;
    int h = hw >> 7, w = hw & 127;
    int hw_base = (blockIdx.x & 63) * 256;

    const unsigned short* fbase = (const unsigned short*)bfeat;
    int l = tid & 63, wv = tid >> 6;
    int arow = l & 15, kg = l >> 4;

    // ---- phase 3 FIRST: roi bilinear issued before MFMA so latency hides ----
    float ysv = (float)h * (63.f / 127.f);
    float y0f = fminf(floorf(ysv), 62.f);
    float wy = ysv - y0f;
    float xsv = (float)w * (63.f / 127.f);
    float x0f = fminf(floorf(xsv), 62.f);
    float wx = xsv - x0f;
    int y0i = (int)y0f, x0i = (int)x0f;
    const float* rb = roi + (size_t)b * 4096;
    float r00 = rb[y0i * 64 + x0i], r01 = rb[y0i * 64 + x0i + 1];
    float r10 = rb[(y0i + 1) * 64 + x0i], r11 = rb[(y0i + 1) * 64 + x0i + 1];
    float rv = r00 * (1.f - wy) * (1.f - wx) + r01 * (1.f - wy) * wx
             + r10 * wy * (1.f - wx) + r11 * wy * wx;

    // ---- phase 1: y = (w1*sc) @ feats_cat via MFMA 16x16x32 bf16 ----
    f32x4 acc[4][4];
#pragma unroll
    for (int mt = 0; mt < 4; ++mt)
#pragma unroll
        for (int nt = 0; nt < 4; ++nt)
            acc[mt][nt] = (f32x4){0.f, 0.f, 0.f, 0.f};

#pragma unroll 2      // 2 K-rounds of loads in flight
    for (int ks = 0; ks < 8; ++ks) {
        int k0 = ks * 32 + kg * 8;
        const unsigned short* cp = fbase
            + ((size_t)((k0 >> 6) * 512 + b * 64 + (k0 & 63))) * 16384 + hw_base;
        s8v af[4];
#pragma unroll
        for (int mt = 0; mt < 4; ++mt) {
            const unsigned short* q = cp + wv * 64 + mt * 16 + arow;
            unsigned int u0 = (unsigned int)q[0]         | ((unsigned int)q[16384]     << 16);
            unsigned int u1 = (unsigned int)q[2 * 16384] | ((unsigned int)q[3 * 16384] << 16);
            unsigned int u2 = (unsigned int)q[4 * 16384] | ((unsigned int)q[5 * 16384] << 16);
            unsigned int u3 = (unsigned int)q[6 * 16384] | ((unsigned int)q[7 * 16384] << 16);
            uint4v au; au.x = u0; au.y = u1; au.z = u2; au.w = u3;
            af[mt] = __builtin_bit_cast(s8v, au);
        }
        s8v bfr[4];
#pragma unroll
        for (int nt = 0; nt < 4; ++nt) {
            uint4v bu = *(const uint4v*)(w1f + (((nt * 8 + ks) * 64 + l) << 2));
            bfr[nt] = __builtin_bit_cast(s8v, bu);
        }
#pragma unroll
        for (int mt = 0; mt < 4; ++mt)
#pragma unroll
            for (int nt = 0; nt < 4; ++nt)
                acc[mt][nt] = __builtin_amdgcn_mfma_f32_16x16x32_bf16(
                    af[mt], bfr[nt], acc[mt][nt], 0, 0, 0);
    }

    // ---- scatter D fragments to LDS ----
#pragma unroll
    for (int mt = 0; mt < 4; ++mt)
#pragma unroll
        for (int nt = 0; nt < 4; ++nt)
#pragma unroll
            for (int r = 0; r < 4; ++r) {
                int px = wv * 64 + mt * 16 + kg * 4 + r;
                y_lds[px * 72 + nt * 16 + arow] = bf16bits(acc[mt][nt][r]);
            }
    __syncthreads();

    // ---- gather this thread's pixel, bias + relu ----
    float y[64];
    {
        const uint4v* yr = (const uint4v*)(y_lds + (size_t)tid * 72);
#pragma unroll
        for (int q8 = 0; q8 < 8; ++q8) {
            uint4v v = yr[q8];
            y[q8 * 8 + 0] = __uint_as_float(v.x << 16);
            y[q8 * 8 + 1] = __uint_as_float(v.x & 0xffff0000u);
            y[q8 * 8 + 2] = __uint_as_float(v.y << 16);
            y[q8 * 8 + 3] = __uint_as_float(v.y & 0xffff0000u);
            y[q8 * 8 + 4] = __uint_as_float(v.z << 16);
            y[q8 * 8 + 5] = __uint_as_float(v.z & 0xffff0000u);
            y[q8 * 8 + 6] = __uint_as_float(v.w << 16);
            y[q8 * 8 + 7] = __uint_as_float(v.w & 0xffff0000u);
        }
    }
#pragma unroll
    for (int o = 0; o < 64; ++o) y[o] = fmaxf(y[o] + dsh[o], 0.f);

    const unsigned short* fbu = fbase + ((size_t)b * 64) * 16384 + hw;

    // ---- phase 2: logits + softmax ----
    float lg[4];
#pragma unroll
    for (int k = 0; k < 4; ++k) {
        float s = b2[k];
        const float* wr = w2 + k * 64;                   // uniform
#pragma unroll
        for (int o = 0; o < 64; ++o) s = fmaf(wr[o], y[o], s);
        lg[k] = s;
    }
    float mx = fmaxf(fmaxf(lg[0], lg[1]), fmaxf(lg[2], lg[3]));
    float e0 = expf(lg[0] - mx), e1s = expf(lg[1] - mx), e2s = expf(lg[2] - mx), e3s = expf(lg[3] - mx);
    float inv = 1.f / (e0 + e1s + e2s + e3s);

    // fold rv into attention weights, pack as bf16 pairs
    float ar = inv * rv;
    unsigned int pa01 = packbf(e0 * ar, e1s * ar);
    unsigned int pa23 = packbf(e2s * ar, e3s * ar);

    // ---- phase 4: f = sum_i bf_i * (attn_i*rv), via dot2 ----
    float f[64];
#pragma unroll
    for (int cc = 0; cc < 64; ++cc) {
        const unsigned short* pp = fbu + (size_t)cc * 16384;
        unsigned int u01 = (unsigned int)pp[0]
                         | ((unsigned int)pp[(size_t)512 * 16384] << 16);
        unsigned int u23 = (unsigned int)pp[(size_t)1024 * 16384]
                         | ((unsigned int)pp[(size_t)1536 * 16384] << 16);
        f[cc] = dot2bf(u23, pa23, dot2bf(u01, pa01, 0.f));
    }
    unsigned int fpk[32];
#pragma unroll
    for (int q = 0; q < 32; ++q) fpk[q] = packbf(f[2 * q], f[2 * q + 1]);

    // ---- phase 5: edge MLP layer 1 via dot2 (BN scale folded) + relu ----
    float eh[32];
#pragma unroll
    for (int o = 0; o < 32; ++o) {
        float s = 0.f;
        const unsigned int* wr = ew1p + o * 32;          // uniform -> SGPR
#pragma unroll
        for (int q = 0; q < 32; ++q) s = dot2bf(fpk[q], wr[q], s);
        eh[o] = fmaxf(s + esh[o], 0.f);
    }
    unsigned int ehp[16];
#pragma unroll
    for (int q = 0; q < 16; ++q) ehp[q] = packbf(eh[2 * q], eh[2 * q + 1]);

    // ---- phase 6: e2 = sigmoid(ew2 @ eh + b), out = x*(1+e2) ----
    const float* xp = x + ((size_t)b * 64) * 16384 + hw;
    float* op = out + ((size_t)b * 64) * 16384 + hw;
#pragma unroll 8
    for (int cc = 0; cc < 64; ++cc) {
        float s = eb2[cc];
        const unsigned int* wr = ew2p + cc * 16;         // uniform -> SGPR
#pragma unroll
        for (int q = 0; q < 16; ++q) s = dot2bf(ehp[q], wr[q], s);
        float sg = 1.f / (1.f + expf(-s));
        float xv = xp[(size_t)cc * 16384];
        op[(size_t)cc * 16384] = xv + xv * sg;
    }
}

extern "C" void kernel_launch(void* const* d_in, const int* in_sizes, int n_in,
                              void* d_out, int out_size, void* d_ws, size_t ws_size,
                              hipStream_t stream) {
    const float* x    = (const float*)d_in[0];
    const float* roi  = (const float*)d_in[1];
    const float* bk   = (const float*)d_in[2];
    const float* aw1  = (const float*)d_in[3];
    const float* ab1  = (const float*)d_in[4];
    const float* aw2  = (const float*)d_in[5];
    const float* ab2  = (const float*)d_in[6];
    const float* mw1  = (const float*)d_in[7];
    const float* mb1  = (const float*)d_in[8];
    const float* mw2  = (const float*)d_in[9];
    const float* mb2  = (const float*)d_in[10];
    const float* w1   = (const float*)d_in[11];
    const float* bnw  = (const float*)d_in[12];
    const float* bnb  = (const float*)d_in[13];
    const float* bnm  = (const float*)d_in[14];
    const float* bnv  = (const float*)d_in[15];
    const float* w2   = (const float*)d_in[16];
    const float* b2   = (const float*)d_in[17];
    const float* ew1  = (const float*)d_in[18];
    const float* ebnw = (const float*)d_in[19];
    const float* ebnb = (const float*)d_in[20];
    const float* ebnm = (const float*)d_in[21];
    const float* ebnv = (const float*)d_in[22];
    const float* ew2  = (const float*)d_in[23];
    const float* eb2  = (const float*)d_in[24];

    float* ws     = (float*)d_ws;
    float* pooled = ws;                    // 512
    float* angles = ws + 512;              // 256
    float* mod    = ws + 768;              // 2048
    unsigned int* rotp = (unsigned int*)(ws + 2816);   // 73728 uints
    unsigned int* w1f  = (unsigned int*)(ws + 150272); // 8192 uints (MFMA B-frags)
    float* dsh    = ws + 158464;           // 64
    unsigned int* ew1p = (unsigned int*)(ws + 158528); // 1024
    float* esh    = ws + 159552;           // 32
    unsigned int* ew2p = (unsigned int*)(ws + 159584); // 1024
    __hip_bfloat16* bfeat = (__hip_bfloat16*)(ws + 166720);  // 64 MB

    k_prep<<<1, 256, 0, stream>>>(w1, bnw, bnb, bnm, bnv,
                                  ew1, ebnw, ebnb, ebnm, ebnv, ew2,
                                  w1f, dsh, ew1p, esh, ew2p);
    k_pool<<<512, 256, 0, stream>>>(x, pooled);
    k_mlp<<<32, 64, 0, stream>>>(pooled, aw1, ab1, aw2, ab2, mw1, mb1, mw2, mb2, angles, mod);
    k_rot<<<256, 64, 0, stream>>>(bk, angles, rotp);
    k_conv<<<dim3(16, 64), 256, 0, stream>>>(x, rotp, mod, bfeat);
    k_mega<<<512, 256, 0, stream>>>(x, bfeat, roi, w1f, dsh, w2, b2,
                                    ew1p, esh, ew2p, eb2,
                                    (float*)d_out);
}